// Round 19
// baseline (78.049 us; speedup 1.0000x reference)
//
#include <hip/hip_runtime.h>
#include <hip/hip_bf16.h>
#include <math.h>

#define BB 8192
#define XD 784
#define ZD 10
#define KK 2000
#define HH 300

typedef short short8 __attribute__((ext_vector_type(8)));
typedef float f32x4 __attribute__((ext_vector_type(4)));

__device__ __forceinline__ float sp_(float x) {
    return fmaxf(x, 0.f) + __logf(1.f + __expf(-fabsf(x)));
}
__device__ __forceinline__ float elu_(float x) { return x > 0.f ? x : __expf(x) - 1.f; }
__device__ __forceinline__ unsigned short bf16_(float v) {
    __hip_bfloat16 h = __float2bfloat16(v);
    return __builtin_bit_cast(unsigned short, h);
}
__device__ __forceinline__ float b2f_(unsigned short u) {
    return __builtin_bit_cast(float, (unsigned int)u << 16);
}
__device__ __forceinline__ short8 ld8_(const unsigned short* p) {
    return *reinterpret_cast<const short8*>(p);
}
__device__ __forceinline__ void gl16(const unsigned short* g, unsigned short* l) {
    __builtin_amdgcn_global_load_lds(
        (const __attribute__((address_space(1))) unsigned int*)g,
        (__attribute__((address_space(3))) unsigned int*)l, 16, 0, 0);
}
template<int N> __device__ __forceinline__ void vwait() {
    if constexpr (N == 0) asm volatile("s_waitcnt vmcnt(0)" ::: "memory");
    if constexpr (N == 2) asm volatile("s_waitcnt vmcnt(2)" ::: "memory");
}
// fragment-major write of element (row<32, k) into 2-rowgroup buffer, KS=2
__device__ __forceinline__ void fbw(unsigned short* fb, int row, int k, unsigned short v) {
    fb[(((row >> 4) * 2 + (k >> 5)) * 64 + (row & 15) + (((k >> 3) & 3) << 4)) * 8 + (k & 7)] = v;
}

// ---------------------------------------------------------------------------
// Unified streamed layer on a 32-row slab: C[32][NI*128] = A @ Wt^T.
// 8 waves, wave w owns cols {ni*128 + w*16..+15}. ni-outer / ki-inner, fully
// unrolled. Weights FRAGMENT-MAJOR in global (r18 win). 2-slot wave-private
// LDS ring via global_load_lds, depth-2 prefetch, counted vmcnt(2/0);
// lgkmcnt(0) before re-STAGE closes the ds_read/overwrite race. No barriers
// inside a layer. AG=true: A from GLOBAL frag-major, register dbuf.
// LMODE 0: bf16 elu -> actout. LMODE 1: fp32 c3L (c<20).
// LMODE 2: per-row sum(x*logit - softplus(logit)), x fp32 GLOBAL -> redL.
// LMODE 3: per-lane online logsumexp over ni -> redM/redS (c_k in cols 20/21).
// ---------------------------------------------------------------------------
template<int LMODE, int KP, int KI, int NI, bool AG>
__device__ __forceinline__ void layerS(
    const int tid,
    const unsigned short* __restrict__ actin,   // frag-major (LDS, or global if AG)
    const unsigned short* __restrict__ Wt,
    const float* __restrict__ bias,
    unsigned short* __restrict__ actout,
    float* __restrict__ c3L, float* __restrict__ redL,
    float* __restrict__ redM, float* __restrict__ redS,
    unsigned short* __restrict__ ring,
    const float* __restrict__ xrow)
{
    const int w = tid >> 6, l = tid & 63;
    const int cl = l & 15, hi = l >> 4, g4 = hi << 2;
    constexpr int KS = KP / 32;
    constexpr int NQ = NI * KI;
    unsigned short* ringW = ring + w * 2048;               // 2 slots x 1024 sh
    const unsigned short* bsrc = Wt + l * 8;

    f32x4 acc[2];
    float rA[2][4], rB[2][4];
    #pragma unroll
    for (int rg = 0; rg < 2; ++rg)
        #pragma unroll
        for (int rr = 0; rr < 4; ++rr) {
            rA[rg][rr] = (LMODE == 3) ? -1e30f : 0.f;
            rB[rg][rr] = 0.f;
        }

    auto STAGE = [&](int q) {
        const int ni = q / KI, ki = q % KI, slot = q & 1;
        const unsigned short* s0 = bsrc + (((size_t)(ni * 8 + w) * KS + 2 * ki) << 9);
        gl16(s0,       ringW + slot * 1024);
        gl16(s0 + 512, ringW + slot * 1024 + 512);
    };

    short8 Ara[2][4];
    auto loadA = [&](int ki, int buf) {
        #pragma unroll
        for (int rg2 = 0; rg2 < 2; ++rg2)
            #pragma unroll
            for (int s = 0; s < 2; ++s)
                Ara[buf][rg2 * 2 + s] = ld8_(actin + ((rg2 * KS + ki * 2 + s) * 64 + l) * 8);
    };

    STAGE(0);
    if constexpr (NQ > 1) STAGE(1);
    if constexpr (AG) loadA(0, 0);

    #pragma unroll
    for (int q = 0; q < NQ; ++q) {
        const int ni = q / KI, ki = q % KI, slot = q & 1;
        if (ki == 0) {
            acc[0] = (f32x4){0.f, 0.f, 0.f, 0.f};
            acc[1] = (f32x4){0.f, 0.f, 0.f, 0.f};
        }
        if (q + 1 < NQ) vwait<2>();
        else vwait<0>();
        __builtin_amdgcn_sched_barrier(0);
        short8 b0 = ld8_(ringW + slot * 1024 + l * 8);
        short8 b1 = ld8_(ringW + slot * 1024 + 512 + l * 8);
        short8 a00, a01, a10, a11;
        if constexpr (AG) {
            a00 = Ara[q & 1][0]; a01 = Ara[q & 1][1];
            a10 = Ara[q & 1][2]; a11 = Ara[q & 1][3];
            if (q + 1 < NQ) loadA((q + 1) % KI, (q + 1) & 1);
        } else {
            a00 = ld8_(actin + ((0 * KS + ki * 2 + 0) * 64 + l) * 8);
            a01 = ld8_(actin + ((0 * KS + ki * 2 + 1) * 64 + l) * 8);
            a10 = ld8_(actin + ((1 * KS + ki * 2 + 0) * 64 + l) * 8);
            a11 = ld8_(actin + ((1 * KS + ki * 2 + 1) * 64 + l) * 8);
        }
        asm volatile("s_waitcnt lgkmcnt(0)" ::: "memory");  // ds reads done
        __builtin_amdgcn_sched_barrier(0);
        if (q + 2 < NQ) STAGE(q + 2);      // overwrites slot q&1 (reads done)
        acc[0] = __builtin_amdgcn_mfma_f32_16x16x32_bf16(a00, b0, acc[0], 0, 0, 0);
        acc[0] = __builtin_amdgcn_mfma_f32_16x16x32_bf16(a01, b1, acc[0], 0, 0, 0);
        acc[1] = __builtin_amdgcn_mfma_f32_16x16x32_bf16(a10, b0, acc[1], 0, 0, 0);
        acc[1] = __builtin_amdgcn_mfma_f32_16x16x32_bf16(a11, b1, acc[1], 0, 0, 0);

        if (ki == KI - 1) {
            const int c = ni * 128 + w * 16 + cl;
            if constexpr (LMODE == 0) {
                const float bb = (c < HH) ? bias[c] : 0.f;
                #pragma unroll
                for (int rg = 0; rg < 2; ++rg)
                    #pragma unroll
                    for (int rr = 0; rr < 4; ++rr) {
                        float o = (c < HH) ? elu_(acc[rg][rr] + bb) : 0.f;
                        if (c < 320)
                            actout[((rg * 10 + (c >> 5)) * 64 + (g4 + rr) + (((c >> 3) & 3) << 4)) * 8 + (c & 7)] = bf16_(o);
                    }
            } else if constexpr (LMODE == 1) {
                const int cc = w * 16 + cl;
                if (cc < 20) {
                    #pragma unroll
                    for (int rg = 0; rg < 2; ++rg)
                        #pragma unroll
                        for (int rr = 0; rr < 4; ++rr)
                            c3L[(rg * 16 + g4 + rr) * 24 + cc] = acc[rg][rr] + bias[cc];
                }
            } else if constexpr (LMODE == 2) {
                if (c < XD) {
                    const float bb = bias[c];
                    #pragma unroll
                    for (int rg = 0; rg < 2; ++rg)
                        #pragma unroll
                        for (int rr = 0; rr < 4; ++rr) {
                            float lv = acc[rg][rr] + bb;
                            float xv = xrow[(size_t)(rg * 16 + g4 + rr) * XD + c];
                            rA[rg][rr] += xv * lv - sp_(lv);
                        }
                }
            } else {
                #pragma unroll
                for (int rg = 0; rg < 2; ++rg)
                    #pragma unroll
                    for (int rr = 0; rr < 4; ++rr) {
                        float v = acc[rg][rr];
                        float mx = fmaxf(v, rA[rg][rr]);
                        rB[rg][rr] = rB[rg][rr] * __expf(rA[rg][rr] - mx) + __expf(v - mx);
                        rA[rg][rr] = mx;
                    }
            }
        }
    }

    if constexpr (LMODE == 2) {
        #pragma unroll
        for (int rg = 0; rg < 2; ++rg)
            #pragma unroll
            for (int rr = 0; rr < 4; ++rr) {
                float s = rA[rg][rr];
                s += __shfl_xor(s, 1); s += __shfl_xor(s, 2);
                s += __shfl_xor(s, 4); s += __shfl_xor(s, 8);
                if (cl == 0) redL[(rg * 16 + g4 + rr) * 8 + w] = s;
            }
    }
    if constexpr (LMODE == 3) {
        #pragma unroll
        for (int d = 1; d <= 8; d <<= 1)
            #pragma unroll
            for (int rg = 0; rg < 2; ++rg)
                #pragma unroll
                for (int rr = 0; rr < 4; ++rr) {
                    float mo = __shfl_xor(rA[rg][rr], d);
                    float so = __shfl_xor(rB[rg][rr], d);
                    float M = fmaxf(rA[rg][rr], mo);
                    rB[rg][rr] = rB[rg][rr] * __expf(rA[rg][rr] - M) + so * __expf(mo - M);
                    rA[rg][rr] = M;
                }
        if (cl == 0) {
            #pragma unroll
            for (int rg = 0; rg < 2; ++rg)
                #pragma unroll
                for (int rr = 0; rr < 4; ++rr) {
                    redM[(rg * 16 + g4 + rr) * 8 + w] = rA[rg][rr];
                    redS[(rg * 16 + g4 + rr) * 8 + w] = rB[rg][rr];
                }
        }
    }
}

__global__ __launch_bounds__(512, 2)
void fused_k(const float* __restrict__ xg,
             const unsigned short* __restrict__ xg2,
             const unsigned short* __restrict__ w1t, const float* __restrict__ eb1,
             const unsigned short* __restrict__ w2t, const float* __restrict__ eb2,
             const unsigned short* __restrict__ w3t, const float* __restrict__ eb3,
             const unsigned short* __restrict__ d1t, const float* __restrict__ db1,
             const unsigned short* __restrict__ d2t, const float* __restrict__ db2,
             const unsigned short* __restrict__ d3t, const float* __restrict__ db3,
             const unsigned short* __restrict__ G,
             const float* __restrict__ eps, float* __restrict__ part)
{
    __shared__ __align__(16) unsigned short ring[16384];  // 8 waves x 2 slots x 1024
    __shared__ __align__(16) unsigned short actP[10240];  // 32x320
    __shared__ __align__(16) unsigned short actQ[10240];
    __shared__ __align__(16) unsigned short fbL[2048];    // 32x64
    __shared__ float uredc[800];  // c3L[768] ∪ {redM[256],redS[256],redL[256],lqzL[32]}

    float* c3L  = uredc;
    float* redM = uredc;
    float* redS = uredc + 256;
    float* redL = uredc + 512;
    float* lqzL = uredc + 768;

    const int tid = threadIdx.x;
    const int m0 = blockIdx.x * 32;
    const unsigned short* Aslab = xg2 + (size_t)blockIdx.x * 26624;  // 52*512

    // zero ALL of fbL: 4096B = 256 uint4
    if (tid < 256) reinterpret_cast<uint4*>(fbL)[tid] = (uint4){0u, 0u, 0u, 0u};
    __syncthreads();

    layerS<0, 832, 13, 3, true>(tid, Aslab, w1t, eb1, actP, nullptr, nullptr, nullptr, nullptr, ring, nullptr);
    __syncthreads();
    layerS<0, 320, 5, 3, false>(tid, actP, w2t, eb2, actQ, nullptr, nullptr, nullptr, nullptr, ring, nullptr);
    __syncthreads();
    layerS<1, 320, 5, 1, false>(tid, actQ, w3t, eb3, nullptr, c3L, nullptr, nullptr, nullptr, ring, nullptr);
    __syncthreads();

    if (tid < 32) {
        float a = 0.f;
        float lq;
        #pragma unroll
        for (int j = 0; j < ZD; ++j) {
            float qm = c3L[tid * 24 + j];
            float qh = c3L[tid * 24 + 10 + j];
            float qv = sp_(qh) + 1e-8f;
            float e  = eps[(size_t)(m0 + tid) * ZD + j];
            float zj = qm + sqrtf(qv) * e;
            fbw(fbL, tid, j,      bf16_(zj * zj));
            fbw(fbL, tid, 10 + j, bf16_(zj));
            float d = zj - qm;
            a += __logf(6.283185307179586f * qv) + d * d / qv;
        }
        fbw(fbL, tid, 20, bf16_(1.f));   // picks up c_k hi/lo from G cols 20/21
        fbw(fbL, tid, 21, bf16_(1.f));
        lq = -0.5f * a;
        lqzL[tid] = lq;   // disjoint from c3L (uredc+768)
    }
    __syncthreads();

    layerS<0, 64, 1, 3, false>(tid, fbL, d1t, db1, actP, nullptr, nullptr, nullptr, nullptr, ring, nullptr);
    __syncthreads();
    layerS<0, 320, 5, 3, false>(tid, actP, d2t, db2, actQ, nullptr, nullptr, nullptr, nullptr, ring, nullptr);
    __syncthreads();
    layerS<2, 320, 5, 7, false>(tid, actQ, d3t, db3, nullptr, nullptr, redL, nullptr, nullptr, ring,
                                xg + (size_t)m0 * XD);
    __syncthreads();
    layerS<3, 64, 1, 16, false>(tid, fbL, G, nullptr, nullptr, nullptr, nullptr, redM, redS, ring, nullptr);
    __syncthreads();

    if (tid < 32) {
        float M = -1e30f, S = 0.f;
        #pragma unroll
        for (int w8 = 0; w8 < 8; ++w8) {
            float m = redM[tid * 8 + w8], s = redS[tid * 8 + w8];
            float M2 = fmaxf(M, m);
            S = S * __expf(M - M2) + s * __expf(m - M2);
            M = M2;
        }
        float lpz = M + __logf(S) - 7.6009024595420824f;  // log(2000)
        float lpx = 0.f;
        #pragma unroll
        for (int w8 = 0; w8 < 8; ++w8) lpx += redL[tid * 8 + w8];
        float kl = lqzL[tid] - lpz;
        float ne = kl - lpx, re = -lpx;
        #pragma unroll
        for (int d = 1; d <= 16; d <<= 1) {
            ne += __shfl_xor(ne, d); kl += __shfl_xor(kl, d); re += __shfl_xor(re, d);
        }
        if (tid == 0) {
            part[blockIdx.x * 3 + 0] = ne;
            part[blockIdx.x * 3 + 1] = kl;
            part[blockIdx.x * 3 + 2] = re;
        }
    }
}

// ---------------------------------------------------------------------------
// prep: weights -> FRAGMENT-MAJOR bf16 (r18 layout); GMM coefs with c_k
// hi/lo at k=20/21; x -> bf16 frag-major xg2 (256 slabs x 52 chunks).
// ---------------------------------------------------------------------------
__global__ __launch_bounds__(256)
void prep_k(const float* __restrict__ x,
            const float* __restrict__ ew1, const float* __restrict__ ew2,
            const float* __restrict__ ew3, const float* __restrict__ dw1,
            const float* __restrict__ dw2, const float* __restrict__ dw3,
            const float* __restrict__ zpre,
            unsigned short* __restrict__ w1t, unsigned short* __restrict__ w2t,
            unsigned short* __restrict__ w3t, unsigned short* __restrict__ d1t,
            unsigned short* __restrict__ d2t, unsigned short* __restrict__ d3t,
            unsigned short* __restrict__ G, unsigned short* __restrict__ xg2)
{
    const int t = blockIdx.x * 256 + threadIdx.x;
    const int y = blockIdx.y;
    const int lane = t & 63, chunk = t >> 6;
    const int cl = lane & 15, hi = lane >> 4;

    auto genw = [&](const float* W, unsigned short* out, int NT, int KS2,
                    int K, int N) {
        if (chunk >= NT * KS2) return;
        const int kc = chunk % KS2, nt = chunk / KS2;
        const int n = nt * 16 + cl, kb = kc * 32 + hi * 8;
        short8 v8;
        #pragma unroll
        for (int e = 0; e < 8; ++e) {
            const int k = kb + e;
            v8[e] = (short)bf16_((n < N && k < K) ? W[(size_t)k * N + n] : 0.f);
        }
        *reinterpret_cast<short8*>(&out[(size_t)t * 8]) = v8;
    };

    if (y == 0) genw(ew1, w1t, 24, 26, XD, HH);
    else if (y == 1) genw(ew2, w2t, 24, 10, HH, HH);
    else if (y == 2) genw(ew3, w3t, 8, 10, HH, 2 * ZD);
    else if (y == 3) {          // d1t: rows k=10..19 hold dw1 (fb layout)
        if (chunk >= 24 * 2) return;
        const int kc = chunk & 1, nt = chunk >> 1;
        const int n = nt * 16 + cl, kb = kc * 32 + hi * 8;
        short8 v8;
        #pragma unroll
        for (int e = 0; e < 8; ++e) {
            const int k = kb + e;
            float v = (n < HH && k >= 10 && k < 20) ? dw1[(size_t)(k - 10) * HH + n] : 0.f;
            v8[e] = (short)bf16_(v);
        }
        *reinterpret_cast<short8*>(&d1t[(size_t)t * 8]) = v8;
    }
    else if (y == 4) genw(dw2, d2t, 24, 10, HH, HH);
    else if (y == 5) genw(dw3, d3t, 56, 10, HH, XD);
    else if (y == 6) {          // G: NT=128, KS2=2; c_k hi/lo at k=20/21
        if (chunk >= 128 * 2) return;
        const int kc = chunk & 1, nt = chunk >> 1;
        const int n = nt * 16 + cl, kb = kc * 32 + hi * 8;
        float ck = 0.f;
        if (n < KK && kb == 16) {
            float csum = 0.f;
            #pragma unroll
            for (int j = 0; j < ZD; ++j) {
                float m = zpre[n * ZD + j];
                float h = zpre[(KK + n) * ZD + j];
                float v = sp_(h) + 1e-8f;
                csum += __logf(6.283185307179586f * v) + m * m / v;
            }
            ck = -0.5f * csum;
        }
        short8 v8;
        #pragma unroll
        for (int e = 0; e < 8; ++e) {
            const int k = kb + e;
            unsigned short us = 0;
            if (n < KK) {
                if (k < 10) {
                    float h = zpre[(KK + n) * ZD + k];
                    float v = sp_(h) + 1e-8f;
                    us = bf16_(-0.5f / v);
                } else if (k < 20) {
                    float m = zpre[n * ZD + (k - 10)];
                    float h = zpre[(KK + n) * ZD + (k - 10)];
                    float v = sp_(h) + 1e-8f;
                    us = bf16_(m / v);
                } else if (k == 20) {
                    us = bf16_(ck);
                } else if (k == 21) {
                    us = bf16_(ck - b2f_(bf16_(ck)));
                }
            } else if (k == 20) {
                us = bf16_(-1e30f);
            }
            v8[e] = (short)us;
        }
        *reinterpret_cast<short8*>(&G[(size_t)t * 8]) = v8;
    } else {
        // xg2: 256 slabs x 52 chunks x 64 lanes x 8 elems (bf16 frag-major)
        if (t >= 256 * 52 * 64) return;
        const int kc2 = chunk % 52, slab = chunk / 52;
        const int rg = kc2 / 26, kc = kc2 % 26;
        const int row = slab * 32 + rg * 16 + cl;
        const int k0 = kc * 32 + hi * 8;
        short8 v8 = (short8){0, 0, 0, 0, 0, 0, 0, 0};
        if (k0 < XD) {
            const float* src = x + (size_t)row * XD + k0;
            float4 f0 = *reinterpret_cast<const float4*>(src);
            float4 f1 = *reinterpret_cast<const float4*>(src + 4);
            v8[0] = (short)bf16_(f0.x); v8[1] = (short)bf16_(f0.y);
            v8[2] = (short)bf16_(f0.z); v8[3] = (short)bf16_(f0.w);
            v8[4] = (short)bf16_(f1.x); v8[5] = (short)bf16_(f1.y);
            v8[6] = (short)bf16_(f1.z); v8[7] = (short)bf16_(f1.w);
        }
        *reinterpret_cast<short8*>(&xg2[(size_t)t * 8]) = v8;
    }
}

__global__ void fin_k(const float* __restrict__ part, float* __restrict__ out)
{
    int c = threadIdx.x >> 6, l = threadIdx.x & 63;
    if (c < 3) {
        float s = 0.f;
        for (int i = l; i < 256; i += 64) s += part[i * 3 + c];
        #pragma unroll
        for (int d = 1; d < 64; d <<= 1) s += __shfl_xor(s, d);
        if (l == 0) out[c] = s / (float)BB;
    }
}

extern "C" void kernel_launch(void* const* d_in, const int* in_sizes, int n_in,
                              void* d_out, int out_size, void* d_ws, size_t ws_size,
                              hipStream_t stream)
{
    const float* x    = (const float*)d_in[0];
    const float* eps  = (const float*)d_in[1];
    const float* zpre = (const float*)d_in[2];
    const float* ew1  = (const float*)d_in[3];
    const float* eb1  = (const float*)d_in[4];
    const float* ew2  = (const float*)d_in[5];
    const float* eb2  = (const float*)d_in[6];
    const float* ew3  = (const float*)d_in[7];
    const float* eb3  = (const float*)d_in[8];
    const float* dw1  = (const float*)d_in[9];
    const float* db1  = (const float*)d_in[10];
    const float* dw2  = (const float*)d_in[11];
    const float* db2  = (const float*)d_in[12];
    const float* dw3  = (const float*)d_in[13];
    const float* db3  = (const float*)d_in[14];
    float* out = (float*)d_out;

    float* ws   = (float*)d_ws;
    float* part = ws;                        // 256*3
    unsigned short* ub = (unsigned short*)(part + 768);
    unsigned short* xg2 = ub; ub += (size_t)256 * 26624;  // 256 slabs x 52 chunks
    unsigned short* w1t = ub; ub += 24 * 26 * 512;
    unsigned short* w2t = ub; ub += 24 * 10 * 512;
    unsigned short* w3t = ub; ub += 8 * 10 * 512;
    unsigned short* d1t = ub; ub += 24 * 2 * 512;
    unsigned short* d2t = ub; ub += 24 * 10 * 512;
    unsigned short* d3t = ub; ub += 56 * 10 * 512;
    unsigned short* G   = ub; ub += 128 * 2 * 512;

    dim3 blk(256);
    prep_k<<<dim3(3328, 8), blk, 0, stream>>>(x, ew1, ew2, ew3, dw1, dw2, dw3, zpre,
                                              w1t, w2t, w3t, d1t, d2t, d3t, G, xg2);
    fused_k<<<256, 512, 0, stream>>>(x, xg2, w1t, eb1, w2t, eb2, w3t, eb3,
                                     d1t, db1, d2t, db2, d3t, db3, G, eps, part);
    fin_k<<<1, 256, 0, stream>>>(part, out);
}

// Round 20
// 75.983 us; speedup vs baseline: 1.0272x; 1.0272x over previous
//
#include <hip/hip_runtime.h>
#include <hip/hip_bf16.h>
#include <math.h>

#define BB 8192
#define XD 784
#define ZD 10
#define KK 2000
#define HH 300

typedef short short8 __attribute__((ext_vector_type(8)));
typedef float f32x4 __attribute__((ext_vector_type(4)));

__device__ __forceinline__ float sp_(float x) {
    return fmaxf(x, 0.f) + __logf(1.f + __expf(-fabsf(x)));
}
__device__ __forceinline__ float elu_(float x) { return x > 0.f ? x : __expf(x) - 1.f; }
__device__ __forceinline__ unsigned short bf16_(float v) {
    __hip_bfloat16 h = __float2bfloat16(v);
    return __builtin_bit_cast(unsigned short, h);
}
__device__ __forceinline__ float b2f_(unsigned short u) {
    return __builtin_bit_cast(float, (unsigned int)u << 16);
}
__device__ __forceinline__ short8 ld8_(const unsigned short* p) {
    return *reinterpret_cast<const short8*>(p);
}
__device__ __forceinline__ void gl16(const unsigned short* g, unsigned short* l) {
    __builtin_amdgcn_global_load_lds(
        (const __attribute__((address_space(1))) unsigned int*)g,
        (__attribute__((address_space(3))) unsigned int*)l, 16, 0, 0);
}
template<int N> __device__ __forceinline__ void vwait() {
    if constexpr (N == 0) asm volatile("s_waitcnt vmcnt(0)" ::: "memory");
    if constexpr (N == 2) asm volatile("s_waitcnt vmcnt(2)" ::: "memory");
    if constexpr (N == 4) asm volatile("s_waitcnt vmcnt(4)" ::: "memory");
    if constexpr (N == 6) asm volatile("s_waitcnt vmcnt(6)" ::: "memory");
}
// fragment-major write of element (row<32, k) into 2-rowgroup buffer, KS=2
__device__ __forceinline__ void fbw(unsigned short* fb, int row, int k, unsigned short v) {
    fb[(((row >> 4) * 2 + (k >> 5)) * 64 + (row & 15) + (((k >> 3) & 3) << 4)) * 8 + (k & 7)] = v;
}

// ---------------------------------------------------------------------------
// 16-wave streamed layer on a 32-row slab: C[32][NI*128] = A @ Wt^T.
// Wave w = (wh=w>>3, wl=w&7): handles ni = 2*nj + wh, cols wl*16..+15 of
// that n-tile. Steps q=(nj,ki), fully unrolled. Weights FRAGMENT-MAJOR
// (r18). Per-wave 3-slot LDS ring via global_load_lds, counted waits:
// steady vmcnt(2) [stage(q) landed; stage(q+1) in flight]; AG adds 4
// A-register loads/step -> vmcnt(6). Inactive waves (ni>=NI on odd tails)
// stage/compute redundantly from ni=NI-1 (uniform counts), stores and
// accumulates guarded by `act`. No barriers inside a layer.
// LMODE 0: bf16 elu -> actout. LMODE 1: fp32 c3L (c<20, wh==0).
// LMODE 2: per-row sum(x*logit-softplus), x fp32 global -> redL[row][16].
// LMODE 3: per-lane online logsumexp -> redM/redS[row][16].
// ---------------------------------------------------------------------------
template<int LMODE, int KP, int KI, int NI, bool AG>
__device__ __forceinline__ void layerS(
    const int tid,
    const unsigned short* __restrict__ actin,   // frag-major (LDS; global if AG)
    const unsigned short* __restrict__ Wt,
    const float* __restrict__ bias,
    unsigned short* __restrict__ actout,
    float* __restrict__ c3L, float* __restrict__ redL,
    float* __restrict__ redM, float* __restrict__ redS,
    unsigned short* __restrict__ ring,
    const float* __restrict__ xrow)
{
    const int w = tid >> 6, l = tid & 63;
    const int wl = w & 7, wh = w >> 3;
    const int cl = l & 15, hi = l >> 4, g4 = hi << 2;
    constexpr int KS = KP / 32;
    constexpr int NJ = (NI + 1) / 2;
    constexpr int NQ = NJ * KI;
    unsigned short* ringW = ring + w * 3072;               // 3 slots x 1024 sh
    const unsigned short* bsrc = Wt + l * 8;

    f32x4 acc[2];
    float rA[2][4], rB[2][4];
    #pragma unroll
    for (int rg = 0; rg < 2; ++rg)
        #pragma unroll
        for (int rr = 0; rr < 4; ++rr) {
            rA[rg][rr] = (LMODE == 3) ? -1e30f : 0.f;
            rB[rg][rr] = 0.f;
        }

    auto niOf = [&](int nj) {
        int ni = 2 * nj + wh;
        return ni < NI ? ni : NI - 1;
    };
    auto STAGE = [&](int q) {
        const int nj = q / KI, ki = q % KI, slot = q % 3;
        const int ni = niOf(nj);
        const unsigned short* s0 = bsrc + (((size_t)(ni * 8 + wl) * KS + 2 * ki) << 9);
        gl16(s0,       ringW + slot * 1024);
        gl16(s0 + 512, ringW + slot * 1024 + 512);
    };

    short8 Ara[2][4];
    auto loadA = [&](int ki, int buf) {
        #pragma unroll
        for (int rg2 = 0; rg2 < 2; ++rg2)
            #pragma unroll
            for (int s = 0; s < 2; ++s)
                Ara[buf][rg2 * 2 + s] = ld8_(actin + ((rg2 * KS + ki * 2 + s) * 64 + l) * 8);
    };

    STAGE(0);
    if constexpr (NQ > 1) STAGE(1);
    if constexpr (AG) loadA(0, 0);

    #pragma unroll
    for (int q = 0; q < NQ; ++q) {
        const int nj = q / KI, ki = q % KI, slot = q % 3;
        const bool act = (2 * nj + wh) < NI;
        if (ki == 0) {
            acc[0] = (f32x4){0.f, 0.f, 0.f, 0.f};
            acc[1] = (f32x4){0.f, 0.f, 0.f, 0.f};
        }
        const int rem = NQ - 1 - q;
        if constexpr (AG) {
            if (rem >= 1) vwait<6>();
            else vwait<4>();
        } else {
            if (rem >= 1) vwait<2>();
            else vwait<0>();
        }
        __builtin_amdgcn_sched_barrier(0);
        short8 b0 = ld8_(ringW + slot * 1024 + l * 8);
        short8 b1 = ld8_(ringW + slot * 1024 + 512 + l * 8);
        short8 a00, a01, a10, a11;
        if constexpr (AG) {
            a00 = Ara[q & 1][0]; a01 = Ara[q & 1][1];
            a10 = Ara[q & 1][2]; a11 = Ara[q & 1][3];
            if (q + 1 < NQ) loadA((q + 1) % KI, (q + 1) & 1);
        } else {
            a00 = ld8_(actin + ((0 * KS + ki * 2 + 0) * 64 + l) * 8);
            a01 = ld8_(actin + ((0 * KS + ki * 2 + 1) * 64 + l) * 8);
            a10 = ld8_(actin + ((1 * KS + ki * 2 + 0) * 64 + l) * 8);
            a11 = ld8_(actin + ((1 * KS + ki * 2 + 1) * 64 + l) * 8);
        }
        if (q + 2 < NQ) STAGE(q + 2);      // slot (q+2)%3: not read for 2 steps
        acc[0] = __builtin_amdgcn_mfma_f32_16x16x32_bf16(a00, b0, acc[0], 0, 0, 0);
        acc[0] = __builtin_amdgcn_mfma_f32_16x16x32_bf16(a01, b1, acc[0], 0, 0, 0);
        acc[1] = __builtin_amdgcn_mfma_f32_16x16x32_bf16(a10, b0, acc[1], 0, 0, 0);
        acc[1] = __builtin_amdgcn_mfma_f32_16x16x32_bf16(a11, b1, acc[1], 0, 0, 0);

        if (ki == KI - 1) {
            const int c = (2 * nj + wh) * 128 + wl * 16 + cl;   // valid iff act
            if constexpr (LMODE == 0) {
                const float bb = (act && c < HH) ? bias[c] : 0.f;
                #pragma unroll
                for (int rg = 0; rg < 2; ++rg)
                    #pragma unroll
                    for (int rr = 0; rr < 4; ++rr) {
                        float o = (c < HH) ? elu_(acc[rg][rr] + bb) : 0.f;
                        if (act && c < 320)
                            actout[((rg * 10 + (c >> 5)) * 64 + (g4 + rr) + (((c >> 3) & 3) << 4)) * 8 + (c & 7)] = bf16_(o);
                    }
            } else if constexpr (LMODE == 1) {
                const int cc = wl * 16 + cl;
                if (act && cc < 20) {
                    #pragma unroll
                    for (int rg = 0; rg < 2; ++rg)
                        #pragma unroll
                        for (int rr = 0; rr < 4; ++rr)
                            c3L[(rg * 16 + g4 + rr) * 24 + cc] = acc[rg][rr] + bias[cc];
                }
            } else if constexpr (LMODE == 2) {
                if (act && c < XD) {
                    const float bb = bias[c];
                    #pragma unroll
                    for (int rg = 0; rg < 2; ++rg)
                        #pragma unroll
                        for (int rr = 0; rr < 4; ++rr) {
                            float lv = acc[rg][rr] + bb;
                            float xv = xrow[(size_t)(rg * 16 + g4 + rr) * XD + c];
                            rA[rg][rr] += xv * lv - sp_(lv);
                        }
                }
            } else {
                if (act) {
                    #pragma unroll
                    for (int rg = 0; rg < 2; ++rg)
                        #pragma unroll
                        for (int rr = 0; rr < 4; ++rr) {
                            float v = acc[rg][rr];
                            float mx = fmaxf(v, rA[rg][rr]);
                            rB[rg][rr] = rB[rg][rr] * __expf(rA[rg][rr] - mx) + __expf(v - mx);
                            rA[rg][rr] = mx;
                        }
                }
            }
        }
    }

    if constexpr (LMODE == 2) {
        #pragma unroll
        for (int rg = 0; rg < 2; ++rg)
            #pragma unroll
            for (int rr = 0; rr < 4; ++rr) {
                float s = rA[rg][rr];
                s += __shfl_xor(s, 1); s += __shfl_xor(s, 2);
                s += __shfl_xor(s, 4); s += __shfl_xor(s, 8);
                if (cl == 0) redL[(rg * 16 + g4 + rr) * 16 + w] = s;
            }
    }
    if constexpr (LMODE == 3) {
        #pragma unroll
        for (int d = 1; d <= 8; d <<= 1)
            #pragma unroll
            for (int rg = 0; rg < 2; ++rg)
                #pragma unroll
                for (int rr = 0; rr < 4; ++rr) {
                    float mo = __shfl_xor(rA[rg][rr], d);
                    float so = __shfl_xor(rB[rg][rr], d);
                    float M = fmaxf(rA[rg][rr], mo);
                    rB[rg][rr] = rB[rg][rr] * __expf(rA[rg][rr] - M) + so * __expf(mo - M);
                    rA[rg][rr] = M;
                }
        if (cl == 0) {
            #pragma unroll
            for (int rg = 0; rg < 2; ++rg)
                #pragma unroll
                for (int rr = 0; rr < 4; ++rr) {
                    redM[(rg * 16 + g4 + rr) * 16 + w] = rA[rg][rr];
                    redS[(rg * 16 + g4 + rr) * 16 + w] = rB[rg][rr];
                }
        }
    }
}

__global__ __launch_bounds__(1024, 1)
void fused_k(const float* __restrict__ xg,
             const unsigned short* __restrict__ xg2,
             const unsigned short* __restrict__ w1t, const float* __restrict__ eb1,
             const unsigned short* __restrict__ w2t, const float* __restrict__ eb2,
             const unsigned short* __restrict__ w3t, const float* __restrict__ eb3,
             const unsigned short* __restrict__ d1t, const float* __restrict__ db1,
             const unsigned short* __restrict__ d2t, const float* __restrict__ db2,
             const unsigned short* __restrict__ d3t, const float* __restrict__ db3,
             const unsigned short* __restrict__ G,
             const float* __restrict__ eps, float* __restrict__ part)
{
    __shared__ __align__(16) unsigned short ring[49152];  // 16 waves x 3 x 1024
    __shared__ __align__(16) unsigned short actP[10240];  // 32x320 frag-major
    __shared__ __align__(16) unsigned short actQ[10240];
    __shared__ __align__(16) unsigned short fbL[2048];    // 32x64
    __shared__ float uredc[1568];  // c3L[768] ∪ {redM[512],redS[512],redL[512],lqzL[32]}

    float* c3L  = uredc;
    float* redM = uredc;
    float* redS = uredc + 512;
    float* redL = uredc + 1024;
    float* lqzL = uredc + 1536;

    const int tid = threadIdx.x;
    const int m0 = blockIdx.x * 32;
    const unsigned short* Aslab = xg2 + (size_t)blockIdx.x * 26624;  // 52*512

    // zero ALL of fbL: sizeof(fbL)=4096B = 256 uint4
    if (tid < 256) reinterpret_cast<uint4*>(fbL)[tid] = (uint4){0u, 0u, 0u, 0u};
    __syncthreads();

    layerS<0, 832, 13, 3, true>(tid, Aslab, w1t, eb1, actP, nullptr, nullptr, nullptr, nullptr, ring, nullptr);
    __syncthreads();
    layerS<0, 320, 5, 3, false>(tid, actP, w2t, eb2, actQ, nullptr, nullptr, nullptr, nullptr, ring, nullptr);
    __syncthreads();
    layerS<1, 320, 5, 1, false>(tid, actQ, w3t, eb3, nullptr, c3L, nullptr, nullptr, nullptr, ring, nullptr);
    __syncthreads();

    if (tid < 32) {
        float a = 0.f;
        #pragma unroll
        for (int j = 0; j < ZD; ++j) {
            float qm = c3L[tid * 24 + j];
            float qh = c3L[tid * 24 + 10 + j];
            float qv = sp_(qh) + 1e-8f;
            float e  = eps[(size_t)(m0 + tid) * ZD + j];
            float zj = qm + sqrtf(qv) * e;
            fbw(fbL, tid, j,      bf16_(zj * zj));
            fbw(fbL, tid, 10 + j, bf16_(zj));
            float d = zj - qm;
            a += __logf(6.283185307179586f * qv) + d * d / qv;
        }
        fbw(fbL, tid, 20, bf16_(1.f));   // picks up c_k hi/lo from G cols 20/21
        fbw(fbL, tid, 21, bf16_(1.f));
        lqzL[tid] = -0.5f * a;   // uredc+1536, disjoint from c3L
    }
    __syncthreads();

    layerS<0, 64, 1, 3, false>(tid, fbL, d1t, db1, actP, nullptr, nullptr, nullptr, nullptr, ring, nullptr);
    __syncthreads();
    layerS<0, 320, 5, 3, false>(tid, actP, d2t, db2, actQ, nullptr, nullptr, nullptr, nullptr, ring, nullptr);
    __syncthreads();
    layerS<2, 320, 5, 7, false>(tid, actQ, d3t, db3, nullptr, nullptr, redL, nullptr, nullptr, ring,
                                xg + (size_t)m0 * XD);
    __syncthreads();
    layerS<3, 64, 1, 16, false>(tid, fbL, G, nullptr, nullptr, nullptr, nullptr, redM, redS, ring, nullptr);
    __syncthreads();

    if (tid < 32) {
        float M = -1e30f, S = 0.f;
        #pragma unroll
        for (int w16 = 0; w16 < 16; ++w16) {
            float m = redM[tid * 16 + w16], s = redS[tid * 16 + w16];
            float M2 = fmaxf(M, m);
            S = S * __expf(M - M2) + s * __expf(m - M2);
            M = M2;
        }
        float lpz = M + __logf(S) - 7.6009024595420824f;  // log(2000)
        float lpx = 0.f;
        #pragma unroll
        for (int w16 = 0; w16 < 16; ++w16) lpx += redL[tid * 16 + w16];
        float kl = lqzL[tid] - lpz;
        float ne = kl - lpx, re = -lpx;
        #pragma unroll
        for (int d = 1; d <= 16; d <<= 1) {
            ne += __shfl_xor(ne, d); kl += __shfl_xor(kl, d); re += __shfl_xor(re, d);
        }
        if (tid == 0) {
            part[blockIdx.x * 3 + 0] = ne;
            part[blockIdx.x * 3 + 1] = kl;
            part[blockIdx.x * 3 + 2] = re;
        }
    }
}

// ---------------------------------------------------------------------------
// prep: weights -> FRAGMENT-MAJOR bf16; GMM coefs with c_k hi/lo at k=20/21;
// x -> bf16 frag-major xg2 (256 slabs x 52 chunks).
// ---------------------------------------------------------------------------
__global__ __launch_bounds__(256)
void prep_k(const float* __restrict__ x,
            const float* __restrict__ ew1, const float* __restrict__ ew2,
            const float* __restrict__ ew3, const float* __restrict__ dw1,
            const float* __restrict__ dw2, const float* __restrict__ dw3,
            const float* __restrict__ zpre,
            unsigned short* __restrict__ w1t, unsigned short* __restrict__ w2t,
            unsigned short* __restrict__ w3t, unsigned short* __restrict__ d1t,
            unsigned short* __restrict__ d2t, unsigned short* __restrict__ d3t,
            unsigned short* __restrict__ G, unsigned short* __restrict__ xg2)
{
    const int t = blockIdx.x * 256 + threadIdx.x;
    const int y = blockIdx.y;
    const int lane = t & 63, chunk = t >> 6;
    const int cl = lane & 15, hi = lane >> 4;

    auto genw = [&](const float* W, unsigned short* out, int NT, int KS2,
                    int K, int N) {
        if (chunk >= NT * KS2) return;
        const int kc = chunk % KS2, nt = chunk / KS2;
        const int n = nt * 16 + cl, kb = kc * 32 + hi * 8;
        short8 v8;
        #pragma unroll
        for (int e = 0; e < 8; ++e) {
            const int k = kb + e;
            v8[e] = (short)bf16_((n < N && k < K) ? W[(size_t)k * N + n] : 0.f);
        }
        *reinterpret_cast<short8*>(&out[(size_t)t * 8]) = v8;
    };

    if (y == 0) genw(ew1, w1t, 24, 26, XD, HH);
    else if (y == 1) genw(ew2, w2t, 24, 10, HH, HH);
    else if (y == 2) genw(ew3, w3t, 8, 10, HH, 2 * ZD);
    else if (y == 3) {          // d1t: rows k=10..19 hold dw1 (fb layout)
        if (chunk >= 24 * 2) return;
        const int kc = chunk & 1, nt = chunk >> 1;
        const int n = nt * 16 + cl, kb = kc * 32 + hi * 8;
        short8 v8;
        #pragma unroll
        for (int e = 0; e < 8; ++e) {
            const int k = kb + e;
            float v = (n < HH && k >= 10 && k < 20) ? dw1[(size_t)(k - 10) * HH + n] : 0.f;
            v8[e] = (short)bf16_(v);
        }
        *reinterpret_cast<short8*>(&d1t[(size_t)t * 8]) = v8;
    }
    else if (y == 4) genw(dw2, d2t, 24, 10, HH, HH);
    else if (y == 5) genw(dw3, d3t, 56, 10, HH, XD);
    else if (y == 6) {          // G: NT=128, KS2=2; c_k hi/lo at k=20/21
        if (chunk >= 128 * 2) return;
        const int kc = chunk & 1, nt = chunk >> 1;
        const int n = nt * 16 + cl, kb = kc * 32 + hi * 8;
        float ck = 0.f;
        if (n < KK && kb == 16) {
            float csum = 0.f;
            #pragma unroll
            for (int j = 0; j < ZD; ++j) {
                float m = zpre[n * ZD + j];
                float h = zpre[(KK + n) * ZD + j];
                float v = sp_(h) + 1e-8f;
                csum += __logf(6.283185307179586f * v) + m * m / v;
            }
            ck = -0.5f * csum;
        }
        short8 v8;
        #pragma unroll
        for (int e = 0; e < 8; ++e) {
            const int k = kb + e;
            unsigned short us = 0;
            if (n < KK) {
                if (k < 10) {
                    float h = zpre[(KK + n) * ZD + k];
                    float v = sp_(h) + 1e-8f;
                    us = bf16_(-0.5f / v);
                } else if (k < 20) {
                    float m = zpre[n * ZD + (k - 10)];
                    float h = zpre[(KK + n) * ZD + (k - 10)];
                    float v = sp_(h) + 1e-8f;
                    us = bf16_(m / v);
                } else if (k == 20) {
                    us = bf16_(ck);
                } else if (k == 21) {
                    us = bf16_(ck - b2f_(bf16_(ck)));
                }
            } else if (k == 20) {
                us = bf16_(-1e30f);
            }
            v8[e] = (short)us;
        }
        *reinterpret_cast<short8*>(&G[(size_t)t * 8]) = v8;
    } else {
        // xg2: 256 slabs x 52 chunks x 64 lanes x 8 elems (bf16 frag-major)
        if (t >= 256 * 52 * 64) return;
        const int kc2 = chunk % 52, slab = chunk / 52;
        const int rg = kc2 / 26, kc = kc2 % 26;
        const int row = slab * 32 + rg * 16 + cl;
        const int k0 = kc * 32 + hi * 8;
        short8 v8 = (short8){0, 0, 0, 0, 0, 0, 0, 0};
        if (k0 < XD) {
            const float* src = x + (size_t)row * XD + k0;
            float4 f0 = *reinterpret_cast<const float4*>(src);
            float4 f1 = *reinterpret_cast<const float4*>(src + 4);
            v8[0] = (short)bf16_(f0.x); v8[1] = (short)bf16_(f0.y);
            v8[2] = (short)bf16_(f0.z); v8[3] = (short)bf16_(f0.w);
            v8[4] = (short)bf16_(f1.x); v8[5] = (short)bf16_(f1.y);
            v8[6] = (short)bf16_(f1.z); v8[7] = (short)bf16_(f1.w);
        }
        *reinterpret_cast<short8*>(&xg2[(size_t)t * 8]) = v8;
    }
}

__global__ void fin_k(const float* __restrict__ part, float* __restrict__ out)
{
    int c = threadIdx.x >> 6, l = threadIdx.x & 63;
    if (c < 3) {
        float s = 0.f;
        for (int i = l; i < 256; i += 64) s += part[i * 3 + c];
        #pragma unroll
        for (int d = 1; d < 64; d <<= 1) s += __shfl_xor(s, d);
        if (l == 0) out[c] = s / (float)BB;
    }
}

extern "C" void kernel_launch(void* const* d_in, const int* in_sizes, int n_in,
                              void* d_out, int out_size, void* d_ws, size_t ws_size,
                              hipStream_t stream)
{
    const float* x    = (const float*)d_in[0];
    const float* eps  = (const float*)d_in[1];
    const float* zpre = (const float*)d_in[2];
    const float* ew1  = (const float*)d_in[3];
    const float* eb1  = (const float*)d_in[4];
    const float* ew2  = (const float*)d_in[5];
    const float* eb2  = (const float*)d_in[6];
    const float* ew3  = (const float*)d_in[7];
    const float* eb3  = (const float*)d_in[8];
    const float* dw1  = (const float*)d_in[9];
    const float* db1  = (const float*)d_in[10];
    const float* dw2  = (const float*)d_in[11];
    const float* db2  = (const float*)d_in[12];
    const float* dw3  = (const float*)d_in[13];
    const float* db3  = (const float*)d_in[14];
    float* out = (float*)d_out;

    float* ws   = (float*)d_ws;
    float* part = ws;                        // 256*3
    unsigned short* ub = (unsigned short*)(part + 768);
    unsigned short* xg2 = ub; ub += (size_t)256 * 26624;
    unsigned short* w1t = ub; ub += 24 * 26 * 512;
    unsigned short* w2t = ub; ub += 24 * 10 * 512;
    unsigned short* w3t = ub; ub += 8 * 10 * 512;
    unsigned short* d1t = ub; ub += 24 * 2 * 512;
    unsigned short* d2t = ub; ub += 24 * 10 * 512;
    unsigned short* d3t = ub; ub += 56 * 10 * 512;
    unsigned short* G   = ub; ub += 128 * 2 * 512;

    dim3 blk(256);
    prep_k<<<dim3(3328, 8), blk, 0, stream>>>(x, ew1, ew2, ew3, dw1, dw2, dw3, zpre,
                                              w1t, w2t, w3t, d1t, d2t, d3t, G, xg2);
    fused_k<<<256, 1024, 0, stream>>>(x, xg2, w1t, eb1, w2t, eb2, w3t, eb3,
                                      d1t, db1, d2t, db2, d3t, db3, G, eps, part);
    fin_k<<<1, 256, 0, stream>>>(part, out);
}

// Round 21
// 70.013 us; speedup vs baseline: 1.1148x; 1.0853x over previous
//
#include <hip/hip_runtime.h>
#include <hip/hip_bf16.h>
#include <math.h>

#define BB 8192
#define XD 784
#define ZD 10
#define KK 2000
#define HH 300

typedef short short8 __attribute__((ext_vector_type(8)));
typedef float f32x4 __attribute__((ext_vector_type(4)));

__device__ __forceinline__ float sp_(float x) {
    return fmaxf(x, 0.f) + __logf(1.f + __expf(-fabsf(x)));
}
__device__ __forceinline__ float elu_(float x) { return x > 0.f ? x : __expf(x) - 1.f; }
__device__ __forceinline__ unsigned short bf16_(float v) {
    __hip_bfloat16 h = __float2bfloat16(v);
    return __builtin_bit_cast(unsigned short, h);
}
__device__ __forceinline__ float b2f_(unsigned short u) {
    return __builtin_bit_cast(float, (unsigned int)u << 16);
}
__device__ __forceinline__ short8 ld8_(const unsigned short* p) {
    return *reinterpret_cast<const short8*>(p);
}
// fragment-major write of element (row<32, k) into 2-rowgroup buffer, KS=2
__device__ __forceinline__ void fbw(unsigned short* fb, int row, int k, unsigned short v) {
    fb[(((row >> 4) * 2 + (k >> 5)) * 64 + (row & 15) + (((k >> 3) & 3) << 4)) * 8 + (k & 7)] = v;
}

// ---------------------------------------------------------------------------
// 16-wave register-streamed layer on a 32-row slab: C[32][NI*128] = A @ Wt^T.
// Wave w=(wh=w>>3, wl=w&7) handles n-tiles ni=2*nj+wh, cols wl*16..+15.
// ki-MAJOR: A read once per ki (4 ds_read / or register-dbuf global if AG),
// shared by this wave's n-tiles; B = DIRECT global->VGPR (fragment-major
// layout -> 16B/lane coalesced), double-buffered over ki (prefetch dist = 1
// ki; 4 waves/SIMD interleave covers L2 latency). NO LDS staging of B at
// all. NJ>2 handled in register passes of <=2 n-tiles (VGPR cap).
// Inactive tail n-tiles: loads clamped to NI-1, stores/accums guarded.
// LMODE 0: bf16 elu -> actout. LMODE 1: fp32 c3L (c<20).
// LMODE 2: per-row sum(x*logit - softplus(logit)), x fp32 global -> redL.
// ---------------------------------------------------------------------------
template<int LMODE, int KP, int KI, int NI, bool AG>
__device__ __forceinline__ void layerR(
    const int tid,
    const unsigned short* __restrict__ actin,   // frag-major (LDS; global if AG)
    const unsigned short* __restrict__ Wt,
    const float* __restrict__ bias,
    unsigned short* __restrict__ actout,
    float* __restrict__ c3L, float* __restrict__ redL,
    const float* __restrict__ xrow)
{
    const int w = tid >> 6, l = tid & 63;
    const int wl = w & 7, wh = w >> 3;
    const int cl = l & 15, hi = l >> 4, g4 = hi << 2;
    constexpr int KS = KP / 32;
    constexpr int NJ = (NI + 1) / 2;       // n-tiles per wave
    constexpr int NP = (NJ + 1) / 2;       // register passes (<=2 tiles each)
    const unsigned short* bsrc = Wt + l * 8;

    float rA[2][4];
    #pragma unroll
    for (int rg = 0; rg < 2; ++rg)
        #pragma unroll
        for (int rr = 0; rr < 4; ++rr) rA[rg][rr] = 0.f;

    #pragma unroll
    for (int p = 0; p < NP; ++p) {
        f32x4 acc[2][2];
        #pragma unroll
        for (int j = 0; j < 2; ++j)
            #pragma unroll
            for (int rg = 0; rg < 2; ++rg) acc[j][rg] = (f32x4){0.f, 0.f, 0.f, 0.f};

        // clamped ni per j (compile-time j, runtime wh)
        int niC[2], rawv[2];
        #pragma unroll
        for (int j = 0; j < 2; ++j) {
            const int njIdx = 2 * p + j;
            const int raw = (njIdx < NJ) ? (2 * njIdx + wh) : (NI - 1);
            rawv[j] = (njIdx < NJ) ? (2 * njIdx + wh) : NI;   // NI => inactive
            niC[j] = (raw < NI) ? raw : (NI - 1);
        }

        short8 Bb[2][2][2];
        short8 Ab[2][4];
        #pragma unroll
        for (int j = 0; j < 2; ++j) {
            const unsigned short* s0 = bsrc + (((size_t)(niC[j] * 8 + wl) * KS) << 9);
            Bb[0][j][0] = ld8_(s0);
            Bb[0][j][1] = ld8_(s0 + 512);
        }
        if constexpr (AG) {
            #pragma unroll
            for (int rg = 0; rg < 2; ++rg)
                #pragma unroll
                for (int s = 0; s < 2; ++s)
                    Ab[0][rg * 2 + s] = ld8_(actin + ((rg * KS + s) * 64 + l) * 8);
        }

        #pragma unroll
        for (int ki = 0; ki < KI; ++ki) {
            const int cur = ki & 1, nxt = cur ^ 1;
            if (ki + 1 < KI) {
                #pragma unroll
                for (int j = 0; j < 2; ++j) {
                    const unsigned short* s0 = bsrc +
                        (((size_t)(niC[j] * 8 + wl) * KS + 2 * (ki + 1)) << 9);
                    Bb[nxt][j][0] = ld8_(s0);
                    Bb[nxt][j][1] = ld8_(s0 + 512);
                }
                if constexpr (AG) {
                    #pragma unroll
                    for (int rg = 0; rg < 2; ++rg)
                        #pragma unroll
                        for (int s = 0; s < 2; ++s)
                            Ab[nxt][rg * 2 + s] = ld8_(actin + ((rg * KS + (ki + 1) * 2 + s) * 64 + l) * 8);
                }
            }
            short8 a[4];
            if constexpr (AG) {
                #pragma unroll
                for (int u = 0; u < 4; ++u) a[u] = Ab[cur][u];
            } else {
                #pragma unroll
                for (int rg = 0; rg < 2; ++rg)
                    #pragma unroll
                    for (int s = 0; s < 2; ++s)
                        a[rg * 2 + s] = ld8_(actin + ((rg * KS + ki * 2 + s) * 64 + l) * 8);
            }
            #pragma unroll
            for (int j = 0; j < 2; ++j)
                #pragma unroll
                for (int rg = 0; rg < 2; ++rg) {
                    acc[j][rg] = __builtin_amdgcn_mfma_f32_16x16x32_bf16(a[rg * 2 + 0], Bb[cur][j][0], acc[j][rg], 0, 0, 0);
                    acc[j][rg] = __builtin_amdgcn_mfma_f32_16x16x32_bf16(a[rg * 2 + 1], Bb[cur][j][1], acc[j][rg], 0, 0, 0);
                }
        }

        // epilogue for this pass
        #pragma unroll
        for (int j = 0; j < 2; ++j) {
            const bool act = rawv[j] < NI;
            const int c = rawv[j] * 128 + wl * 16 + cl;   // meaningful iff act
            if constexpr (LMODE == 0) {
                const float bb = (act && c < HH) ? bias[c] : 0.f;
                #pragma unroll
                for (int rg = 0; rg < 2; ++rg)
                    #pragma unroll
                    for (int rr = 0; rr < 4; ++rr) {
                        float o = (c < HH) ? elu_(acc[j][rg][rr] + bb) : 0.f;
                        if (act && c < 320)
                            actout[((rg * 10 + (c >> 5)) * 64 + (g4 + rr) + (((c >> 3) & 3) << 4)) * 8 + (c & 7)] = bf16_(o);
                    }
            } else if constexpr (LMODE == 1) {
                const int cc = wl * 16 + cl;
                if (act && cc < 20) {
                    #pragma unroll
                    for (int rg = 0; rg < 2; ++rg)
                        #pragma unroll
                        for (int rr = 0; rr < 4; ++rr)
                            c3L[(rg * 16 + g4 + rr) * 24 + cc] = acc[j][rg][rr] + bias[cc];
                }
            } else {
                if (act && c < XD) {
                    const float bb = bias[c];
                    #pragma unroll
                    for (int rg = 0; rg < 2; ++rg)
                        #pragma unroll
                        for (int rr = 0; rr < 4; ++rr) {
                            float lv = acc[j][rg][rr] + bb;
                            float xv = xrow[(size_t)(rg * 16 + g4 + rr) * XD + c];
                            rA[rg][rr] += xv * lv - sp_(lv);
                        }
                }
            }
        }
    }

    if constexpr (LMODE == 2) {
        #pragma unroll
        for (int rg = 0; rg < 2; ++rg)
            #pragma unroll
            for (int rr = 0; rr < 4; ++rr) {
                float s = rA[rg][rr];
                s += __shfl_xor(s, 1); s += __shfl_xor(s, 2);
                s += __shfl_xor(s, 4); s += __shfl_xor(s, 8);
                if (cl == 0) redL[(rg * 16 + g4 + rr) * 16 + w] = s;
            }
    }
}

// ---------------------------------------------------------------------------
// comp: KP=64, NI=16 -> each wave streams its 8 n-tiles (ni=2*nj+wh), B in
// register dbuf, A (fbL) in regs once; per-lane online logsumexp; one
// cross-lane merge -> redM/redS[row][16].
// ---------------------------------------------------------------------------
__device__ __forceinline__ void layerC(
    const int tid,
    const unsigned short* __restrict__ fbL,
    const unsigned short* __restrict__ G,
    float* __restrict__ redM, float* __restrict__ redS)
{
    const int w = tid >> 6, l = tid & 63;
    const int wl = w & 7, wh = w >> 3;
    const int cl = l & 15, hi = l >> 4, g4 = hi << 2;
    const unsigned short* bsrc = G + l * 8;

    short8 a[4];
    #pragma unroll
    for (int rg = 0; rg < 2; ++rg)
        #pragma unroll
        for (int s = 0; s < 2; ++s)
            a[rg * 2 + s] = ld8_(fbL + ((rg * 2 + s) * 64 + l) * 8);

    float rA[2][4], rB[2][4];
    #pragma unroll
    for (int rg = 0; rg < 2; ++rg)
        #pragma unroll
        for (int rr = 0; rr < 4; ++rr) { rA[rg][rr] = -1e30f; rB[rg][rr] = 0.f; }

    const unsigned short* s00 = bsrc + (((size_t)(wh * 8 + wl) * 2) << 9);
    short8 c0 = ld8_(s00), c1 = ld8_(s00 + 512);
    #pragma unroll
    for (int nj = 0; nj < 8; ++nj) {
        short8 p0 = c0, p1 = c1;
        if (nj + 1 < 8) {
            const int ni = 2 * (nj + 1) + wh;
            const unsigned short* s0 = bsrc + (((size_t)(ni * 8 + wl) * 2) << 9);
            p0 = ld8_(s0);
            p1 = ld8_(s0 + 512);
        }
        f32x4 acc[2];
        #pragma unroll
        for (int rg = 0; rg < 2; ++rg) {
            acc[rg] = __builtin_amdgcn_mfma_f32_16x16x32_bf16(a[rg * 2 + 0], c0, (f32x4){0.f, 0.f, 0.f, 0.f}, 0, 0, 0);
            acc[rg] = __builtin_amdgcn_mfma_f32_16x16x32_bf16(a[rg * 2 + 1], c1, acc[rg], 0, 0, 0);
        }
        #pragma unroll
        for (int rg = 0; rg < 2; ++rg)
            #pragma unroll
            for (int rr = 0; rr < 4; ++rr) {
                float v = acc[rg][rr];
                float mx = fmaxf(v, rA[rg][rr]);
                rB[rg][rr] = rB[rg][rr] * __expf(rA[rg][rr] - mx) + __expf(v - mx);
                rA[rg][rr] = mx;
            }
        c0 = p0; c1 = p1;
    }
    #pragma unroll
    for (int d = 1; d <= 8; d <<= 1)
        #pragma unroll
        for (int rg = 0; rg < 2; ++rg)
            #pragma unroll
            for (int rr = 0; rr < 4; ++rr) {
                float mo = __shfl_xor(rA[rg][rr], d);
                float so = __shfl_xor(rB[rg][rr], d);
                float M = fmaxf(rA[rg][rr], mo);
                rB[rg][rr] = rB[rg][rr] * __expf(rA[rg][rr] - M) + so * __expf(mo - M);
                rA[rg][rr] = M;
            }
    if (cl == 0) {
        #pragma unroll
        for (int rg = 0; rg < 2; ++rg)
            #pragma unroll
            for (int rr = 0; rr < 4; ++rr) {
                redM[(rg * 16 + g4 + rr) * 16 + w] = rA[rg][rr];
                redS[(rg * 16 + g4 + rr) * 16 + w] = rB[rg][rr];
            }
    }
}

__global__ __launch_bounds__(1024, 1)
void fused_k(const float* __restrict__ xg,
             const unsigned short* __restrict__ xg2,
             const unsigned short* __restrict__ w1t, const float* __restrict__ eb1,
             const unsigned short* __restrict__ w2t, const float* __restrict__ eb2,
             const unsigned short* __restrict__ w3t, const float* __restrict__ eb3,
             const unsigned short* __restrict__ d1t, const float* __restrict__ db1,
             const unsigned short* __restrict__ d2t, const float* __restrict__ db2,
             const unsigned short* __restrict__ d3t, const float* __restrict__ db3,
             const unsigned short* __restrict__ G,
             const float* __restrict__ eps, float* __restrict__ part)
{
    __shared__ __align__(16) unsigned short actP[10240];  // 32x320 frag-major
    __shared__ __align__(16) unsigned short actQ[10240];
    __shared__ __align__(16) unsigned short fbL[2048];    // 32x64
    __shared__ float uredc[1568];  // c3L[768] ∪ {redM[512],redS[512],redL[512],lqzL[32]}

    float* c3L  = uredc;
    float* redM = uredc;
    float* redS = uredc + 512;
    float* redL = uredc + 1024;
    float* lqzL = uredc + 1536;

    const int tid = threadIdx.x;
    const int m0 = blockIdx.x * 32;
    const unsigned short* Aslab = xg2 + (size_t)blockIdx.x * 26624;  // 52*512

    // zero ALL of fbL: sizeof(fbL)=4096B = 256 uint4
    if (tid < 256) reinterpret_cast<uint4*>(fbL)[tid] = (uint4){0u, 0u, 0u, 0u};
    __syncthreads();

    layerR<0, 832, 13, 3, true>(tid, Aslab, w1t, eb1, actP, nullptr, nullptr, nullptr);
    __syncthreads();
    layerR<0, 320, 5, 3, false>(tid, actP, w2t, eb2, actQ, nullptr, nullptr, nullptr);
    __syncthreads();
    layerR<1, 320, 5, 1, false>(tid, actQ, w3t, eb3, nullptr, c3L, nullptr, nullptr);
    __syncthreads();

    if (tid < 32) {
        float a = 0.f;
        #pragma unroll
        for (int j = 0; j < ZD; ++j) {
            float qm = c3L[tid * 24 + j];
            float qh = c3L[tid * 24 + 10 + j];
            float qv = sp_(qh) + 1e-8f;
            float e  = eps[(size_t)(m0 + tid) * ZD + j];
            float zj = qm + sqrtf(qv) * e;
            fbw(fbL, tid, j,      bf16_(zj * zj));
            fbw(fbL, tid, 10 + j, bf16_(zj));
            float d = zj - qm;
            a += __logf(6.283185307179586f * qv) + d * d / qv;
        }
        fbw(fbL, tid, 20, bf16_(1.f));   // picks up c_k hi/lo from G cols 20/21
        fbw(fbL, tid, 21, bf16_(1.f));
        lqzL[tid] = -0.5f * a;   // uredc+1536, disjoint from c3L
    }
    __syncthreads();

    layerR<0, 64, 1, 3, false>(tid, fbL, d1t, db1, actP, nullptr, nullptr, nullptr);
    __syncthreads();
    layerR<0, 320, 5, 3, false>(tid, actP, d2t, db2, actQ, nullptr, nullptr, nullptr);
    __syncthreads();
    layerR<2, 320, 5, 7, false>(tid, actQ, d3t, db3, nullptr, nullptr, redL,
                                xg + (size_t)m0 * XD);
    __syncthreads();
    layerC(tid, fbL, G, redM, redS);
    __syncthreads();

    if (tid < 32) {
        float M = -1e30f, S = 0.f;
        #pragma unroll
        for (int w16 = 0; w16 < 16; ++w16) {
            float m = redM[tid * 16 + w16], s = redS[tid * 16 + w16];
            float M2 = fmaxf(M, m);
            S = S * __expf(M - M2) + s * __expf(m - M2);
            M = M2;
        }
        float lpz = M + __logf(S) - 7.6009024595420824f;  // log(2000)
        float lpx = 0.f;
        #pragma unroll
        for (int w16 = 0; w16 < 16; ++w16) lpx += redL[tid * 16 + w16];
        float kl = lqzL[tid] - lpz;
        float ne = kl - lpx, re = -lpx;
        #pragma unroll
        for (int d = 1; d <= 16; d <<= 1) {
            ne += __shfl_xor(ne, d); kl += __shfl_xor(kl, d); re += __shfl_xor(re, d);
        }
        if (tid == 0) {
            part[blockIdx.x * 3 + 0] = ne;
            part[blockIdx.x * 3 + 1] = kl;
            part[blockIdx.x * 3 + 2] = re;
        }
    }
}

// ---------------------------------------------------------------------------
// prep: weights -> FRAGMENT-MAJOR bf16; GMM coefs with c_k hi/lo at k=20/21;
// x -> bf16 frag-major xg2 (256 slabs x 52 chunks).
// ---------------------------------------------------------------------------
__global__ __launch_bounds__(256)
void prep_k(const float* __restrict__ x,
            const float* __restrict__ ew1, const float* __restrict__ ew2,
            const float* __restrict__ ew3, const float* __restrict__ dw1,
            const float* __restrict__ dw2, const float* __restrict__ dw3,
            const float* __restrict__ zpre,
            unsigned short* __restrict__ w1t, unsigned short* __restrict__ w2t,
            unsigned short* __restrict__ w3t, unsigned short* __restrict__ d1t,
            unsigned short* __restrict__ d2t, unsigned short* __restrict__ d3t,
            unsigned short* __restrict__ G, unsigned short* __restrict__ xg2)
{
    const int t = blockIdx.x * 256 + threadIdx.x;
    const int y = blockIdx.y;
    const int lane = t & 63, chunk = t >> 6;
    const int cl = lane & 15, hi = lane >> 4;

    auto genw = [&](const float* W, unsigned short* out, int NT, int KS2,
                    int K, int N) {
        if (chunk >= NT * KS2) return;
        const int kc = chunk % KS2, nt = chunk / KS2;
        const int n = nt * 16 + cl, kb = kc * 32 + hi * 8;
        short8 v8;
        #pragma unroll
        for (int e = 0; e < 8; ++e) {
            const int k = kb + e;
            v8[e] = (short)bf16_((n < N && k < K) ? W[(size_t)k * N + n] : 0.f);
        }
        *reinterpret_cast<short8*>(&out[(size_t)t * 8]) = v8;
    };

    if (y == 0) genw(ew1, w1t, 24, 26, XD, HH);
    else if (y == 1) genw(ew2, w2t, 24, 10, HH, HH);
    else if (y == 2) genw(ew3, w3t, 8, 10, HH, 2 * ZD);
    else if (y == 3) {          // d1t: rows k=10..19 hold dw1 (fb layout)
        if (chunk >= 24 * 2) return;
        const int kc = chunk & 1, nt = chunk >> 1;
        const int n = nt * 16 + cl, kb = kc * 32 + hi * 8;
        short8 v8;
        #pragma unroll
        for (int e = 0; e < 8; ++e) {
            const int k = kb + e;
            float v = (n < HH && k >= 10 && k < 20) ? dw1[(size_t)(k - 10) * HH + n] : 0.f;
            v8[e] = (short)bf16_(v);
        }
        *reinterpret_cast<short8*>(&d1t[(size_t)t * 8]) = v8;
    }
    else if (y == 4) genw(dw2, d2t, 24, 10, HH, HH);
    else if (y == 5) genw(dw3, d3t, 56, 10, HH, XD);
    else if (y == 6) {          // G: NT=128, KS2=2; c_k hi/lo at k=20/21
        if (chunk >= 128 * 2) return;
        const int kc = chunk & 1, nt = chunk >> 1;
        const int n = nt * 16 + cl, kb = kc * 32 + hi * 8;
        float ck = 0.f;
        if (n < KK && kb == 16) {
            float csum = 0.f;
            #pragma unroll
            for (int j = 0; j < ZD; ++j) {
                float m = zpre[n * ZD + j];
                float h = zpre[(KK + n) * ZD + j];
                float v = sp_(h) + 1e-8f;
                csum += __logf(6.283185307179586f * v) + m * m / v;
            }
            ck = -0.5f * csum;
        }
        short8 v8;
        #pragma unroll
        for (int e = 0; e < 8; ++e) {
            const int k = kb + e;
            unsigned short us = 0;
            if (n < KK) {
                if (k < 10) {
                    float h = zpre[(KK + n) * ZD + k];
                    float v = sp_(h) + 1e-8f;
                    us = bf16_(-0.5f / v);
                } else if (k < 20) {
                    float m = zpre[n * ZD + (k - 10)];
                    float h = zpre[(KK + n) * ZD + (k - 10)];
                    float v = sp_(h) + 1e-8f;
                    us = bf16_(m / v);
                } else if (k == 20) {
                    us = bf16_(ck);
                } else if (k == 21) {
                    us = bf16_(ck - b2f_(bf16_(ck)));
                }
            } else if (k == 20) {
                us = bf16_(-1e30f);
            }
            v8[e] = (short)us;
        }
        *reinterpret_cast<short8*>(&G[(size_t)t * 8]) = v8;
    } else {
        // xg2: 256 slabs x 52 chunks x 64 lanes x 8 elems (bf16 frag-major)
        if (t >= 256 * 52 * 64) return;
        const int kc2 = chunk % 52, slab = chunk / 52;
        const int rg = kc2 / 26, kc = kc2 % 26;
        const int row = slab * 32 + rg * 16 + cl;
        const int k0 = kc * 32 + hi * 8;
        short8 v8 = (short8){0, 0, 0, 0, 0, 0, 0, 0};
        if (k0 < XD) {
            const float* src = x + (size_t)row * XD + k0;
            float4 f0 = *reinterpret_cast<const float4*>(src);
            float4 f1 = *reinterpret_cast<const float4*>(src + 4);
            v8[0] = (short)bf16_(f0.x); v8[1] = (short)bf16_(f0.y);
            v8[2] = (short)bf16_(f0.z); v8[3] = (short)bf16_(f0.w);
            v8[4] = (short)bf16_(f1.x); v8[5] = (short)bf16_(f1.y);
            v8[6] = (short)bf16_(f1.z); v8[7] = (short)bf16_(f1.w);
        }
        *reinterpret_cast<short8*>(&xg2[(size_t)t * 8]) = v8;
    }
}

__global__ void fin_k(const float* __restrict__ part, float* __restrict__ out)
{
    int c = threadIdx.x >> 6, l = threadIdx.x & 63;
    if (c < 3) {
        float s = 0.f;
        for (int i = l; i < 256; i += 64) s += part[i * 3 + c];
        #pragma unroll
        for (int d = 1; d < 64; d <<= 1) s += __shfl_xor(s, d);
        if (l == 0) out[c] = s / (float)BB;
    }
}

extern "C" void kernel_launch(void* const* d_in, const int* in_sizes, int n_in,
                              void* d_out, int out_size, void* d_ws, size_t ws_size,
                              hipStream_t stream)
{
    const float* x    = (const float*)d_in[0];
    const float* eps  = (const float*)d_in[1];
    const float* zpre = (const float*)d_in[2];
    const float* ew1  = (const float*)d_in[3];
    const float* eb1  = (const float*)d_in[4];
    const float* ew2  = (const float*)d_in[5];
    const float* eb2  = (const float*)d_in[6];
    const float* ew3  = (const float*)d_in[7];
    const float* eb3  = (const float*)d_in[8];
    const float* dw1  = (const float*)d_in[9];
    const float* db1  = (const float*)d_in[10];
    const float* dw2  = (const float*)d_in[11];
    const float* db2  = (const float*)d_in[12];
    const float* dw3  = (const float*)d_in[13];
    const float* db3  = (const float*)d_in[14];
    float* out = (float*)d_out;

    float* ws   = (float*)d_ws;
    float* part = ws;                        // 256*3
    unsigned short* ub = (unsigned short*)(part + 768);
    unsigned short* xg2 = ub; ub += (size_t)256 * 26624;
    unsigned short* w1t = ub; ub += 24 * 26 * 512;
    unsigned short* w2t = ub; ub += 24 * 10 * 512;
    unsigned short* w3t = ub; ub += 8 * 10 * 512;
    unsigned short* d1t = ub; ub += 24 * 2 * 512;
    unsigned short* d2t = ub; ub += 24 * 10 * 512;
    unsigned short* d3t = ub; ub += 56 * 10 * 512;
    unsigned short* G   = ub; ub += 128 * 2 * 512;

    dim3 blk(256);
    prep_k<<<dim3(3328, 8), blk, 0, stream>>>(x, ew1, ew2, ew3, dw1, dw2, dw3, zpre,
                                              w1t, w2t, w3t, d1t, d2t, d3t, G, xg2);
    fused_k<<<256, 1024, 0, stream>>>(x, xg2, w1t, eb1, w2t, eb2, w3t, eb3,
                                      d1t, db1, d2t, db2, d3t, db3, G, eps, part);
    fin_k<<<1, 256, 0, stream>>>(part, out);
}

// Round 22
// 57.464 us; speedup vs baseline: 1.3582x; 1.2184x over previous
//
#include <hip/hip_runtime.h>
#include <hip/hip_bf16.h>
#include <hip/hip_fp8.h>
#include <math.h>

#define BB 8192
#define XD 784
#define ZD 10
#define KK 2000
#define HH 300

typedef unsigned char uchar16 __attribute__((ext_vector_type(16)));
typedef long lng2 __attribute__((ext_vector_type(2)));
typedef float f32x4 __attribute__((ext_vector_type(4)));

__device__ __forceinline__ float sp_(float x) {
    return fmaxf(x, 0.f) + __logf(1.f + __expf(-fabsf(x)));
}
__device__ __forceinline__ float elu_(float x) { return x > 0.f ? x : __expf(x) - 1.f; }
__device__ __forceinline__ unsigned char f8_(float v) {
    __hip_fp8_e4m3 t(v);
    return (unsigned char)t.__x;
}
__device__ __forceinline__ uchar16 ld16_(const unsigned char* p) {
    return *reinterpret_cast<const uchar16*>(p);
}
// fp8 MFMA over one 16B chunk pair (K=64): bytes 0..7 = k base+ (hi*8..), 8..15 = +32
__device__ __forceinline__ void mm64(f32x4& acc, uchar16 a, uchar16 b) {
    lng2 la = __builtin_bit_cast(lng2, a);
    lng2 lb = __builtin_bit_cast(lng2, b);
    acc = __builtin_amdgcn_mfma_f32_16x16x32_fp8_fp8(la[0], lb[0], acc, 0, 0, 0);
    acc = __builtin_amdgcn_mfma_f32_16x16x32_fp8_fp8(la[1], lb[1], acc, 0, 0, 0);
}
// fp8 fragment-major byte index for (rowgroup-chunk base) element (row<16, k<64·KS)
__device__ __forceinline__ int fpi_(int chunk, int row, int k) {
    return ((chunk + (k >> 6)) * 64 + row + (((k >> 3) & 3) << 4)) * 16
           + (k & 7) + (((k >> 5) & 1) << 3);
}

// ---------------------------------------------------------------------------
// 16-wave fp8 register-streamed layer on a 32-row slab.
// Wave w=(wh=w>>3, wl=w&7): n-tiles ni=2*nj+wh, cols wl*16..+15. ki covers
// K=64 (one 16B chunk per operand, 2 MFMAs). B direct global->VGPR (frag-
// major, coalesced), dbuf over ki. A from LDS (or global dbuf if AG).
// acc un-scaled by INV in fp32 epilogue; activations restored with OUTS.
// LMODE 0: fp8 out. LMODE 1: fp32 c3L (c<20). LMODE 2: x-logit rowsum.
// ---------------------------------------------------------------------------
template<int LMODE, int KP, int NI, bool AG>
__device__ __forceinline__ void layerRf(
    const int tid,
    const unsigned char* __restrict__ actin,
    const unsigned char* __restrict__ Wt,
    const float* __restrict__ bias,
    unsigned char* __restrict__ actout,
    float* __restrict__ c3L, float* __restrict__ redL,
    const float* __restrict__ xrow, float INV, float OUTS)
{
    const int w = tid >> 6, l = tid & 63;
    const int wl = w & 7, wh = w >> 3;
    const int cl = l & 15, hi = l >> 4, g4 = hi << 2;
    constexpr int KS = KP / 64;
    constexpr int NJ = (NI + 1) / 2;
    constexpr int NP = (NJ + 1) / 2;
    const unsigned char* bsrc = Wt + l * 16;

    float rA[2][4];
    #pragma unroll
    for (int rg = 0; rg < 2; ++rg)
        #pragma unroll
        for (int rr = 0; rr < 4; ++rr) rA[rg][rr] = 0.f;

    #pragma unroll
    for (int p = 0; p < NP; ++p) {
        f32x4 acc[2][2];
        #pragma unroll
        for (int j = 0; j < 2; ++j)
            #pragma unroll
            for (int rg = 0; rg < 2; ++rg) acc[j][rg] = (f32x4){0.f, 0.f, 0.f, 0.f};

        int niC[2], rawv[2];
        #pragma unroll
        for (int j = 0; j < 2; ++j) {
            const int njIdx = 2 * p + j;
            const int raw = (njIdx < NJ) ? (2 * njIdx + wh) : (NI - 1);
            rawv[j] = (njIdx < NJ) ? (2 * njIdx + wh) : NI;   // NI => inactive
            niC[j] = (raw < NI) ? raw : (NI - 1);
        }

        uchar16 Bb[2][2], Ab[2][2];
        #pragma unroll
        for (int j = 0; j < 2; ++j)
            Bb[0][j] = ld16_(bsrc + (((size_t)(niC[j] * 8 + wl) * KS) << 10));
        if constexpr (AG) {
            #pragma unroll
            for (int rg = 0; rg < 2; ++rg)
                Ab[0][rg] = ld16_(actin + ((rg * KS) * 64 + l) * 16);
        }

        #pragma unroll
        for (int ki = 0; ki < KS; ++ki) {
            const int cur = ki & 1, nxt = cur ^ 1;
            if (ki + 1 < KS) {
                #pragma unroll
                for (int j = 0; j < 2; ++j)
                    Bb[nxt][j] = ld16_(bsrc + (((size_t)(niC[j] * 8 + wl) * KS + ki + 1) << 10));
                if constexpr (AG) {
                    #pragma unroll
                    for (int rg = 0; rg < 2; ++rg)
                        Ab[nxt][rg] = ld16_(actin + ((rg * KS + ki + 1) * 64 + l) * 16);
                }
            }
            uchar16 a[2];
            if constexpr (AG) {
                a[0] = Ab[cur][0]; a[1] = Ab[cur][1];
            } else {
                a[0] = ld16_(actin + ((0 * KS + ki) * 64 + l) * 16);
                a[1] = ld16_(actin + ((1 * KS + ki) * 64 + l) * 16);
            }
            #pragma unroll
            for (int j = 0; j < 2; ++j)
                #pragma unroll
                for (int rg = 0; rg < 2; ++rg)
                    mm64(acc[j][rg], a[rg], Bb[cur][j]);
        }

        #pragma unroll
        for (int j = 0; j < 2; ++j) {
            const bool act = rawv[j] < NI;
            const int c = rawv[j] * 128 + wl * 16 + cl;
            if constexpr (LMODE == 0) {
                const float bb = (act && c < HH) ? bias[c] : 0.f;
                #pragma unroll
                for (int rg = 0; rg < 2; ++rg)
                    #pragma unroll
                    for (int rr = 0; rr < 4; ++rr) {
                        float o = (c < HH) ? elu_(acc[j][rg][rr] * INV + bb) : 0.f;
                        if (act && c < 320)
                            actout[fpi_(rg * 5, g4 + rr, c)] = f8_(o * OUTS);
                    }
            } else if constexpr (LMODE == 1) {
                const int cc = wl * 16 + cl;
                if (act && cc < 20) {
                    #pragma unroll
                    for (int rg = 0; rg < 2; ++rg)
                        #pragma unroll
                        for (int rr = 0; rr < 4; ++rr)
                            c3L[(rg * 16 + g4 + rr) * 24 + cc] = acc[j][rg][rr] * INV + bias[cc];
                }
            } else {
                if (act && c < XD) {
                    const float bb = bias[c];
                    #pragma unroll
                    for (int rg = 0; rg < 2; ++rg)
                        #pragma unroll
                        for (int rr = 0; rr < 4; ++rr) {
                            float lv = acc[j][rg][rr] * INV + bb;
                            float xv = xrow[(size_t)(rg * 16 + g4 + rr) * XD + c];
                            rA[rg][rr] += xv * lv - sp_(lv);
                        }
                }
            }
        }
    }

    if constexpr (LMODE == 2) {
        #pragma unroll
        for (int rg = 0; rg < 2; ++rg)
            #pragma unroll
            for (int rr = 0; rr < 4; ++rr) {
                float s = rA[rg][rr];
                s += __shfl_xor(s, 1); s += __shfl_xor(s, 2);
                s += __shfl_xor(s, 4); s += __shfl_xor(s, 8);
                if (cl == 0) redL[(rg * 16 + g4 + rr) * 16 + w] = s;
            }
    }
}

// comp: KP=64 (KS=1), NI=16 tiles of 128 cols -> 2048 cols; per-lane online
// logsumexp over nj; c_k from fp32 cbias (epilogue); cross-lane merge at end.
__device__ __forceinline__ void layerCf(
    const int tid,
    const unsigned char* __restrict__ fbL,
    const unsigned char* __restrict__ G,
    const float* __restrict__ cbias,
    float* __restrict__ redM, float* __restrict__ redS)
{
    const int w = tid >> 6, l = tid & 63;
    const int wl = w & 7, wh = w >> 3;
    const int cl = l & 15, hi = l >> 4, g4 = hi << 2;
    const unsigned char* bsrc = G + l * 16;

    uchar16 a[2];
    a[0] = ld16_(fbL + (0 * 64 + l) * 16);
    a[1] = ld16_(fbL + (1 * 64 + l) * 16);

    float rA[2][4], rB[2][4];
    #pragma unroll
    for (int rg = 0; rg < 2; ++rg)
        #pragma unroll
        for (int rr = 0; rr < 4; ++rr) { rA[rg][rr] = -1e30f; rB[rg][rr] = 0.f; }

    uchar16 c0 = ld16_(bsrc + (((size_t)(wh * 8 + wl)) << 10));
    #pragma unroll
    for (int nj = 0; nj < 8; ++nj) {
        uchar16 p0 = c0;
        if (nj + 1 < 8)
            p0 = ld16_(bsrc + (((size_t)((2 * (nj + 1) + wh) * 8 + wl)) << 10));
        const int c = ((2 * nj + wh) * 8 + wl) * 16 + cl;
        const float cb = cbias[c];
        f32x4 acc[2];
        #pragma unroll
        for (int rg = 0; rg < 2; ++rg) {
            acc[rg] = (f32x4){0.f, 0.f, 0.f, 0.f};
            mm64(acc[rg], a[rg], c0);
        }
        #pragma unroll
        for (int rg = 0; rg < 2; ++rg)
            #pragma unroll
            for (int rr = 0; rr < 4; ++rr) {
                float v = acc[rg][rr] * (1.f / 256.f) + cb;
                float mx = fmaxf(v, rA[rg][rr]);
                rB[rg][rr] = rB[rg][rr] * __expf(rA[rg][rr] - mx) + __expf(v - mx);
                rA[rg][rr] = mx;
            }
        c0 = p0;
    }
    #pragma unroll
    for (int d = 1; d <= 8; d <<= 1)
        #pragma unroll
        for (int rg = 0; rg < 2; ++rg)
            #pragma unroll
            for (int rr = 0; rr < 4; ++rr) {
                float mo = __shfl_xor(rA[rg][rr], d);
                float so = __shfl_xor(rB[rg][rr], d);
                float M = fmaxf(rA[rg][rr], mo);
                rB[rg][rr] = rB[rg][rr] * __expf(rA[rg][rr] - M) + so * __expf(mo - M);
                rA[rg][rr] = M;
            }
    if (cl == 0) {
        #pragma unroll
        for (int rg = 0; rg < 2; ++rg)
            #pragma unroll
            for (int rr = 0; rr < 4; ++rr) {
                redM[(rg * 16 + g4 + rr) * 16 + w] = rA[rg][rr];
                redS[(rg * 16 + g4 + rr) * 16 + w] = rB[rg][rr];
            }
    }
}

__global__ __launch_bounds__(1024, 1)
void fused_k(const float* __restrict__ xg,
             const unsigned char* __restrict__ xg2,
             const unsigned char* __restrict__ w1t, const float* __restrict__ eb1,
             const unsigned char* __restrict__ w2t, const float* __restrict__ eb2,
             const unsigned char* __restrict__ w3t, const float* __restrict__ eb3,
             const unsigned char* __restrict__ d1t, const float* __restrict__ db1,
             const unsigned char* __restrict__ d2t, const float* __restrict__ db2,
             const unsigned char* __restrict__ d3t, const float* __restrict__ db3,
             const unsigned char* __restrict__ G, const float* __restrict__ cbias,
             const float* __restrict__ eps, float* __restrict__ part)
{
    __shared__ __align__(16) unsigned char actP[10240];  // 32x320 fp8 frag-major
    __shared__ __align__(16) unsigned char actQ[10240];
    __shared__ __align__(16) unsigned char fbL[2048];    // 32x64 fp8
    __shared__ float uredc[1568];  // c3L[768] ∪ {redM[512],redS[512],redL[512],lqzL[32]}

    float* c3L  = uredc;
    float* redM = uredc;
    float* redS = uredc + 512;
    float* redL = uredc + 1024;
    float* lqzL = uredc + 1536;

    const int tid = threadIdx.x;
    const int m0 = blockIdx.x * 32;
    const unsigned char* Aslab = xg2 + (size_t)blockIdx.x * 26624;  // 2*13 chunks

    // zero ALL of fbL: sizeof(fbL)=2048B = 128 uint4
    if (tid < 128) reinterpret_cast<uint4*>(fbL)[tid] = (uint4){0u, 0u, 0u, 0u};
    __syncthreads();

    layerRf<0, 832, 3, true>(tid, Aslab, w1t, eb1, actP, nullptr, nullptr, nullptr,
                             1.f / 1024.f, 16.f);
    __syncthreads();
    layerRf<0, 320, 3, false>(tid, actP, w2t, eb2, actQ, nullptr, nullptr, nullptr,
                              1.f / 1024.f, 16.f);
    __syncthreads();
    layerRf<1, 320, 1, false>(tid, actQ, w3t, eb3, nullptr, c3L, nullptr, nullptr,
                              1.f / 1024.f, 0.f);
    __syncthreads();

    if (tid < 32) {
        float a = 0.f;
        const int rg = tid >> 4, rl = tid & 15;
        #pragma unroll
        for (int j = 0; j < ZD; ++j) {
            float qm = c3L[tid * 24 + j];
            float qh = c3L[tid * 24 + 10 + j];
            float qv = sp_(qh) + 1e-8f;
            float e  = eps[(size_t)(m0 + tid) * ZD + j];
            float zj = qm + sqrtf(qv) * e;
            fbL[fpi_(rg, rl, j)]      = f8_(zj * zj * 4.f);
            fbL[fpi_(rg, rl, 10 + j)] = f8_(zj * 4.f);
            float d = zj - qm;
            a += __logf(6.283185307179586f * qv) + d * d / qv;
        }
        lqzL[tid] = -0.5f * a;   // uredc+1536, disjoint from c3L
    }
    __syncthreads();

    layerRf<0, 64, 3, false>(tid, fbL, d1t, db1, actP, nullptr, nullptr, nullptr,
                             1.f / 64.f, 16.f);
    __syncthreads();
    layerRf<0, 320, 3, false>(tid, actP, d2t, db2, actQ, nullptr, nullptr, nullptr,
                              1.f / 1024.f, 16.f);
    __syncthreads();
    layerRf<2, 320, 7, false>(tid, actQ, d3t, db3, nullptr, nullptr, redL,
                              xg + (size_t)m0 * XD, 1.f / 1024.f, 0.f);
    __syncthreads();
    layerCf(tid, fbL, G, cbias, redM, redS);
    __syncthreads();

    if (tid < 32) {
        float M = -1e30f, S = 0.f;
        #pragma unroll
        for (int w16 = 0; w16 < 16; ++w16) {
            float m = redM[tid * 16 + w16], s = redS[tid * 16 + w16];
            float M2 = fmaxf(M, m);
            S = S * __expf(M - M2) + s * __expf(m - M2);
            M = M2;
        }
        float lpz = M + __logf(S) - 7.6009024595420824f;  // log(2000)
        float lpx = 0.f;
        #pragma unroll
        for (int w16 = 0; w16 < 16; ++w16) lpx += redL[tid * 16 + w16];
        float kl = lqzL[tid] - lpz;
        float ne = kl - lpx, re = -lpx;
        #pragma unroll
        for (int d = 1; d <= 16; d <<= 1) {
            ne += __shfl_xor(ne, d); kl += __shfl_xor(kl, d); re += __shfl_xor(re, d);
        }
        if (tid == 0) {
            part[blockIdx.x * 3 + 0] = ne;
            part[blockIdx.x * 3 + 1] = kl;
            part[blockIdx.x * 3 + 2] = re;
        }
    }
}

// ---------------------------------------------------------------------------
// prep: weights -> fp8 fragment-major (scaled); G (x64) + fp32 cbias;
// x -> fp8 frag-major xg2 (scale 16). Chunk=1KB: 16 cols x 64 k, lane 16B:
// byte e -> k = kc*64 + (e>>3)*32 + hi*8 + (e&7).
// ---------------------------------------------------------------------------
__global__ __launch_bounds__(256)
void prep_k(const float* __restrict__ x,
            const float* __restrict__ ew1, const float* __restrict__ ew2,
            const float* __restrict__ ew3, const float* __restrict__ dw1,
            const float* __restrict__ dw2, const float* __restrict__ dw3,
            const float* __restrict__ zpre,
            unsigned char* __restrict__ w1t, unsigned char* __restrict__ w2t,
            unsigned char* __restrict__ w3t, unsigned char* __restrict__ d1t,
            unsigned char* __restrict__ d2t, unsigned char* __restrict__ d3t,
            unsigned char* __restrict__ G, float* __restrict__ cbias,
            unsigned char* __restrict__ xg2)
{
    const int t = blockIdx.x * 256 + threadIdx.x;
    const int y = blockIdx.y;
    const int lane = t & 63, chunk = t >> 6;
    const int cl = lane & 15, hi = lane >> 4;

    auto genw = [&](const float* W, unsigned char* out, int NT, int KS,
                    int K, int N, float s) {
        if (chunk >= NT * KS) return;
        const int kc = chunk % KS, nt = chunk / KS;
        const int n = nt * 16 + cl;
        uchar16 v;
        #pragma unroll
        for (int e = 0; e < 16; ++e) {
            const int k = kc * 64 + (e >> 3) * 32 + hi * 8 + (e & 7);
            v[e] = f8_((n < N && k < K) ? W[(size_t)k * N + n] * s : 0.f);
        }
        *reinterpret_cast<uchar16*>(&out[(size_t)t * 16]) = v;
    };

    if (y == 0) genw(ew1, w1t, 24, 13, XD, HH, 64.f);
    else if (y == 1) genw(ew2, w2t, 24, 5, HH, HH, 64.f);
    else if (y == 2) genw(ew3, w3t, 8, 5, HH, 2 * ZD, 64.f);
    else if (y == 3) {          // d1t: rows k=10..19 hold dw1 (fb layout), x16
        if (chunk >= 24) return;
        const int nt = chunk;
        const int n = nt * 16 + cl;
        uchar16 v;
        #pragma unroll
        for (int e = 0; e < 16; ++e) {
            const int k = (e >> 3) * 32 + hi * 8 + (e & 7);
            float vv = (n < HH && k >= 10 && k < 20) ? dw1[(size_t)(k - 10) * HH + n] * 16.f : 0.f;
            v[e] = f8_(vv);
        }
        *reinterpret_cast<uchar16*>(&d1t[(size_t)t * 16]) = v;
    }
    else if (y == 4) genw(dw2, d2t, 24, 5, HH, HH, 64.f);
    else if (y == 5) genw(dw3, d3t, 56, 5, HH, XD, 64.f);
    else if (y == 6) {          // G x64 (k<10: -0.5/v*4? no: -0.5/v; 10..19: m/v); cbias fp32
        if (chunk >= 128) return;
        const int nt = chunk;
        const int n = nt * 16 + cl;
        uchar16 v;
        #pragma unroll
        for (int e = 0; e < 16; ++e) {
            const int k = (e >> 3) * 32 + hi * 8 + (e & 7);
            float vv = 0.f;
            if (n < KK) {
                if (k < 10) {
                    float h = zpre[(KK + n) * ZD + k];
                    float vr = sp_(h) + 1e-8f;
                    vv = (-0.5f / vr) * 64.f;
                } else if (k < 20) {
                    float m = zpre[n * ZD + (k - 10)];
                    float h = zpre[(KK + n) * ZD + (k - 10)];
                    float vr = sp_(h) + 1e-8f;
                    vv = (m / vr) * 64.f;
                }
            }
            v[e] = f8_(vv);
        }
        *reinterpret_cast<uchar16*>(&G[(size_t)t * 16]) = v;
        if (hi == 0) {
            float cb = -1e30f;
            if (n < KK) {
                float csum = 0.f;
                #pragma unroll
                for (int j = 0; j < ZD; ++j) {
                    float m = zpre[n * ZD + j];
                    float h = zpre[(KK + n) * ZD + j];
                    float vr = sp_(h) + 1e-8f;
                    csum += __logf(6.283185307179586f * vr) + m * m / vr;
                }
                cb = -0.5f * csum;
            }
            cbias[n] = cb;
        }
    } else {
        // xg2: 256 slabs x (2 rg x 13 kc) chunks; x scaled by 16
        if (chunk >= 256 * 26) return;
        const int kc = chunk % 13;
        const int rg = (chunk / 13) & 1;
        const int slab = chunk / 26;
        const int row = slab * 32 + rg * 16 + cl;
        uchar16 v;
        #pragma unroll
        for (int half = 0; half < 2; ++half) {
            const int kb = kc * 64 + half * 32 + hi * 8;
            float f[8];
            if (kb + 7 < XD) {
                float4 f0 = *reinterpret_cast<const float4*>(&x[(size_t)row * XD + kb]);
                float4 f1 = *reinterpret_cast<const float4*>(&x[(size_t)row * XD + kb + 4]);
                f[0] = f0.x; f[1] = f0.y; f[2] = f0.z; f[3] = f0.w;
                f[4] = f1.x; f[5] = f1.y; f[6] = f1.z; f[7] = f1.w;
            } else {
                #pragma unroll
                for (int e = 0; e < 8; ++e) f[e] = 0.f;
            }
            #pragma unroll
            for (int e = 0; e < 8; ++e) v[half * 8 + e] = f8_(f[e] * 16.f);
        }
        *reinterpret_cast<uchar16*>(&xg2[(size_t)t * 16]) = v;
    }
}

__global__ void fin_k(const float* __restrict__ part, float* __restrict__ out)
{
    int c = threadIdx.x >> 6, l = threadIdx.x & 63;
    if (c < 3) {
        float s = 0.f;
        for (int i = l; i < 256; i += 64) s += part[i * 3 + c];
        #pragma unroll
        for (int d = 1; d < 64; d <<= 1) s += __shfl_xor(s, d);
        if (l == 0) out[c] = s / (float)BB;
    }
}

extern "C" void kernel_launch(void* const* d_in, const int* in_sizes, int n_in,
                              void* d_out, int out_size, void* d_ws, size_t ws_size,
                              hipStream_t stream)
{
    const float* x    = (const float*)d_in[0];
    const float* eps  = (const float*)d_in[1];
    const float* zpre = (const float*)d_in[2];
    const float* ew1  = (const float*)d_in[3];
    const float* eb1  = (const float*)d_in[4];
    const float* ew2  = (const float*)d_in[5];
    const float* eb2  = (const float*)d_in[6];
    const float* ew3  = (const float*)d_in[7];
    const float* eb3  = (const float*)d_in[8];
    const float* dw1  = (const float*)d_in[9];
    const float* db1  = (const float*)d_in[10];
    const float* dw2  = (const float*)d_in[11];
    const float* db2  = (const float*)d_in[12];
    const float* dw3  = (const float*)d_in[13];
    const float* db3  = (const float*)d_in[14];
    float* out = (float*)d_out;

    float* ws    = (float*)d_ws;
    float* part  = ws;                       // 256*3
    float* cbias = part + 768;               // 2048
    unsigned char* ub = (unsigned char*)(cbias + 2048);
    unsigned char* xg2 = ub; ub += (size_t)256 * 26624;  // fp8
    unsigned char* w1t = ub; ub += 24 * 13 * 1024;
    unsigned char* w2t = ub; ub += 24 * 5 * 1024;
    unsigned char* w3t = ub; ub += 8 * 5 * 1024;
    unsigned char* d1t = ub; ub += 24 * 1 * 1024;
    unsigned char* d2t = ub; ub += 24 * 5 * 1024;
    unsigned char* d3t = ub; ub += 56 * 5 * 1024;
    unsigned char* G   = ub; ub += 128 * 1 * 1024;

    dim3 blk(256);
    prep_k<<<dim3(1664, 8), blk, 0, stream>>>(x, ew1, ew2, ew3, dw1, dw2, dw3, zpre,
                                              w1t, w2t, w3t, d1t, d2t, d3t, G, cbias, xg2);
    fused_k<<<256, 1024, 0, stream>>>(x, xg2, w1t, eb1, w2t, eb2, w3t, eb3,
                                      d1t, db1, d2t, db2, d3t, db3, G, cbias, eps, part);
    fin_k<<<1, 256, 0, stream>>>(part, out);
}

// Round 23
// 51.481 us; speedup vs baseline: 1.5161x; 1.1162x over previous
//
#include <hip/hip_runtime.h>
#include <hip/hip_bf16.h>
#include <hip/hip_fp8.h>
#include <math.h>

#define BB 8192
#define XD 784
#define ZD 10
#define KK 2000
#define HH 300

typedef unsigned char uchar16 __attribute__((ext_vector_type(16)));
typedef long lng2 __attribute__((ext_vector_type(2)));
typedef float f32x4 __attribute__((ext_vector_type(4)));

__device__ __forceinline__ float sp_(float x) {
    return fmaxf(x, 0.f) + __logf(1.f + __expf(-fabsf(x)));
}
__device__ __forceinline__ float elu_(float x) { return x > 0.f ? x : __expf(x) - 1.f; }
__device__ __forceinline__ unsigned char f8_(float v) {
    __hip_fp8_e4m3 t(v);
    return (unsigned char)t.__x;
}
__device__ __forceinline__ uchar16 ld16_(const unsigned char* p) {
    return *reinterpret_cast<const uchar16*>(p);
}
// fp8 MFMA over one 16B chunk pair (K=64): bytes 0..7 = first K32 block, 8..15 = second
__device__ __forceinline__ void mm64(f32x4& acc, uchar16 a, uchar16 b) {
    lng2 la = __builtin_bit_cast(lng2, a);
    lng2 lb = __builtin_bit_cast(lng2, b);
    acc = __builtin_amdgcn_mfma_f32_16x16x32_fp8_fp8(la[0], lb[0], acc, 0, 0, 0);
    acc = __builtin_amdgcn_mfma_f32_16x16x32_fp8_fp8(la[1], lb[1], acc, 0, 0, 0);
}
// fp8 fragment-major byte index: chunk base + element (row<16, k)
__device__ __forceinline__ int fpi_(int chunk, int row, int k) {
    return ((chunk + (k >> 6)) * 64 + row + (((k >> 3) & 3) << 4)) * 16
           + (k & 7) + (((k >> 5) & 1) << 3);
}

// ---------------------------------------------------------------------------
// 16-wave fp8 register-streamed layer on a 32-row slab (r22 structure).
// Wave w=(wh=w>>3, wl=w&7): n-tiles ni=2*nj+wh, cols wl*16..+15. B direct
// global->VGPR (frag-major coalesced), dbuf over ki; A from LDS frag-major.
// Compile-time tile-existence: (2p+j)<NJ folds after unroll (enc3's phantom
// second tile deleted); runtime clamp only for wh-dependent odd-NI tails.
// LMODE 0: fp8 out. LMODE 1: fp32 c3L (c<20). LMODE 2: x-logit rowsum.
// ---------------------------------------------------------------------------
template<int LMODE, int KP, int NI>
__device__ __forceinline__ void layerRf(
    const int tid,
    const unsigned char* __restrict__ actin,
    const unsigned char* __restrict__ Wt,
    const float* __restrict__ bias,
    unsigned char* __restrict__ actout,
    float* __restrict__ c3L, float* __restrict__ redL,
    const float* __restrict__ xrow, float INV, float OUTS)
{
    const int w = tid >> 6, l = tid & 63;
    const int wl = w & 7, wh = w >> 3;
    const int cl = l & 15, hi = l >> 4, g4 = hi << 2;
    constexpr int KS = KP / 64;
    constexpr int NJ = (NI + 1) / 2;
    constexpr int NP = (NJ + 1) / 2;
    const unsigned char* bsrc = Wt + l * 16;

    float rA[2][4];
    #pragma unroll
    for (int rg = 0; rg < 2; ++rg)
        #pragma unroll
        for (int rr = 0; rr < 4; ++rr) rA[rg][rr] = 0.f;

    #pragma unroll
    for (int p = 0; p < NP; ++p) {
        f32x4 acc[2][2];
        #pragma unroll
        for (int j = 0; j < 2; ++j)
            #pragma unroll
            for (int rg = 0; rg < 2; ++rg) acc[j][rg] = (f32x4){0.f, 0.f, 0.f, 0.f};

        int niC[2], rawv[2];
        #pragma unroll
        for (int j = 0; j < 2; ++j) {
            const int njIdx = 2 * p + j;
            const int raw = (njIdx < NJ) ? (2 * njIdx + wh) : (NI - 1);
            rawv[j] = (njIdx < NJ) ? (2 * njIdx + wh) : NI;   // NI => inactive
            niC[j] = (raw < NI) ? raw : (NI - 1);
        }

        uchar16 Bb[2][2];
        #pragma unroll
        for (int j = 0; j < 2; ++j)
            if ((2 * p + j) < NJ)
                Bb[0][j] = ld16_(bsrc + (((size_t)(niC[j] * 8 + wl) * KS) << 10));

        #pragma unroll
        for (int ki = 0; ki < KS; ++ki) {
            const int cur = ki & 1, nxt = cur ^ 1;
            if (ki + 1 < KS) {
                #pragma unroll
                for (int j = 0; j < 2; ++j)
                    if ((2 * p + j) < NJ)
                        Bb[nxt][j] = ld16_(bsrc + (((size_t)(niC[j] * 8 + wl) * KS + ki + 1) << 10));
            }
            uchar16 a[2];
            a[0] = ld16_(actin + ((0 * KS + ki) * 64 + l) * 16);
            a[1] = ld16_(actin + ((1 * KS + ki) * 64 + l) * 16);
            #pragma unroll
            for (int j = 0; j < 2; ++j)
                if ((2 * p + j) < NJ)
                    #pragma unroll
                    for (int rg = 0; rg < 2; ++rg)
                        mm64(acc[j][rg], a[rg], Bb[cur][j]);
        }

        #pragma unroll
        for (int j = 0; j < 2; ++j) {
            if ((2 * p + j) >= NJ) continue;   // compile-time dead
            const bool act = rawv[j] < NI;
            const int c = rawv[j] * 128 + wl * 16 + cl;
            if constexpr (LMODE == 0) {
                const float bb = (act && c < HH) ? bias[c] : 0.f;
                #pragma unroll
                for (int rg = 0; rg < 2; ++rg)
                    #pragma unroll
                    for (int rr = 0; rr < 4; ++rr) {
                        float o = (c < HH) ? elu_(acc[j][rg][rr] * INV + bb) : 0.f;
                        if (act && c < 320)
                            actout[fpi_(rg * 5, g4 + rr, c)] = f8_(o * OUTS);
                    }
            } else if constexpr (LMODE == 1) {
                const int cc = wl * 16 + cl;
                if (act && cc < 20) {
                    #pragma unroll
                    for (int rg = 0; rg < 2; ++rg)
                        #pragma unroll
                        for (int rr = 0; rr < 4; ++rr)
                            c3L[(rg * 16 + g4 + rr) * 24 + cc] = acc[j][rg][rr] * INV + bias[cc];
                }
            } else {
                if (act && c < XD) {
                    const float bb = bias[c];
                    #pragma unroll
                    for (int rg = 0; rg < 2; ++rg)
                        #pragma unroll
                        for (int rr = 0; rr < 4; ++rr) {
                            float lv = acc[j][rg][rr] * INV + bb;
                            float xv = xrow[(size_t)(rg * 16 + g4 + rr) * XD + c];
                            rA[rg][rr] += xv * lv - sp_(lv);
                        }
                }
            }
        }
    }

    if constexpr (LMODE == 2) {
        #pragma unroll
        for (int rg = 0; rg < 2; ++rg)
            #pragma unroll
            for (int rr = 0; rr < 4; ++rr) {
                float s = rA[rg][rr];
                s += __shfl_xor(s, 1); s += __shfl_xor(s, 2);
                s += __shfl_xor(s, 4); s += __shfl_xor(s, 8);
                if (cl == 0) redL[(rg * 16 + g4 + rr) * 16 + w] = s;
            }
    }
}

// comp: KP=64 (KS=1), 16 n-tiles; per-lane online logsumexp over nj; c_k from
// fp32 cbias; cross-lane merge at end -> redM/redS[row][16].
__device__ __forceinline__ void layerCf(
    const int tid,
    const unsigned char* __restrict__ fbL,
    const unsigned char* __restrict__ G,
    const float* __restrict__ cbias,
    float* __restrict__ redM, float* __restrict__ redS)
{
    const int w = tid >> 6, l = tid & 63;
    const int wl = w & 7, wh = w >> 3;
    const int cl = l & 15, hi = l >> 4, g4 = hi << 2;
    const unsigned char* bsrc = G + l * 16;

    uchar16 a[2];
    a[0] = ld16_(fbL + (0 * 64 + l) * 16);
    a[1] = ld16_(fbL + (1 * 64 + l) * 16);

    float rA[2][4], rB[2][4];
    #pragma unroll
    for (int rg = 0; rg < 2; ++rg)
        #pragma unroll
        for (int rr = 0; rr < 4; ++rr) { rA[rg][rr] = -1e30f; rB[rg][rr] = 0.f; }

    uchar16 c0 = ld16_(bsrc + (((size_t)(wh * 8 + wl)) << 10));
    #pragma unroll
    for (int nj = 0; nj < 8; ++nj) {
        uchar16 p0 = c0;
        if (nj + 1 < 8)
            p0 = ld16_(bsrc + (((size_t)((2 * (nj + 1) + wh) * 8 + wl)) << 10));
        const int c = ((2 * nj + wh) * 8 + wl) * 16 + cl;
        const float cb = cbias[c];
        f32x4 acc[2];
        #pragma unroll
        for (int rg = 0; rg < 2; ++rg) {
            acc[rg] = (f32x4){0.f, 0.f, 0.f, 0.f};
            mm64(acc[rg], a[rg], c0);
        }
        #pragma unroll
        for (int rg = 0; rg < 2; ++rg)
            #pragma unroll
            for (int rr = 0; rr < 4; ++rr) {
                float v = acc[rg][rr] * (1.f / 256.f) + cb;
                float mx = fmaxf(v, rA[rg][rr]);
                rB[rg][rr] = rB[rg][rr] * __expf(rA[rg][rr] - mx) + __expf(v - mx);
                rA[rg][rr] = mx;
            }
        c0 = p0;
    }
    #pragma unroll
    for (int d = 1; d <= 8; d <<= 1)
        #pragma unroll
        for (int rg = 0; rg < 2; ++rg)
            #pragma unroll
            for (int rr = 0; rr < 4; ++rr) {
                float mo = __shfl_xor(rA[rg][rr], d);
                float so = __shfl_xor(rB[rg][rr], d);
                float M = fmaxf(rA[rg][rr], mo);
                rB[rg][rr] = rB[rg][rr] * __expf(rA[rg][rr] - M) + so * __expf(mo - M);
                rA[rg][rr] = M;
            }
    if (cl == 0) {
        #pragma unroll
        for (int rg = 0; rg < 2; ++rg)
            #pragma unroll
            for (int rr = 0; rr < 4; ++rr) {
                redM[(rg * 16 + g4 + rr) * 16 + w] = rA[rg][rr];
                redS[(rg * 16 + g4 + rr) * 16 + w] = rB[rg][rr];
            }
    }
}

__global__ __launch_bounds__(1024, 1)
void fused_k(const float* __restrict__ xg,
             const unsigned char* __restrict__ w1t, const float* __restrict__ eb1,
             const unsigned char* __restrict__ w2t, const float* __restrict__ eb2,
             const unsigned char* __restrict__ w3t, const float* __restrict__ eb3,
             const unsigned char* __restrict__ d1t, const float* __restrict__ db1,
             const unsigned char* __restrict__ d2t, const float* __restrict__ db2,
             const unsigned char* __restrict__ d3t, const float* __restrict__ db3,
             const unsigned char* __restrict__ G, const float* __restrict__ cbias,
             const float* __restrict__ eps, float* __restrict__ part)
{
    __shared__ __align__(16) unsigned char xsf8[26624];  // 32x832 fp8 frag-major
    __shared__ __align__(16) unsigned char actP[10240];  // 32x320
    __shared__ __align__(16) unsigned char actQ[10240];
    __shared__ __align__(16) unsigned char fbL[2048];    // 32x64
    __shared__ float uredc[1568];

    float* c3L  = uredc;
    float* redM = uredc;
    float* redS = uredc + 512;
    float* redL = uredc + 1024;
    float* lqzL = uredc + 1536;

    const int tid = threadIdx.x;
    const int m0 = blockIdx.x * 32;

    // stage x slab fp32 -> fp8 (x16) into LDS, frag-major [rg*13+kc][lane][16]
    #pragma unroll
    for (int it = 0; it < 2; ++it) {
        const int c = tid + it * 1024;
        if (c < 26 * 64) {
            const int chunk = c >> 6, lane = c & 63;
            const int rg = chunk / 13, kc = chunk % 13;
            const int row = m0 + rg * 16 + (lane & 15);
            const int h2 = lane >> 4;
            uchar16 v;
            #pragma unroll
            for (int half = 0; half < 2; ++half) {
                const int kb = kc * 64 + half * 32 + h2 * 8;
                if (kb + 7 < XD) {
                    float4 f0 = *reinterpret_cast<const float4*>(&xg[(size_t)row * XD + kb]);
                    float4 f1 = *reinterpret_cast<const float4*>(&xg[(size_t)row * XD + kb + 4]);
                    v[half * 8 + 0] = f8_(f0.x * 16.f); v[half * 8 + 1] = f8_(f0.y * 16.f);
                    v[half * 8 + 2] = f8_(f0.z * 16.f); v[half * 8 + 3] = f8_(f0.w * 16.f);
                    v[half * 8 + 4] = f8_(f1.x * 16.f); v[half * 8 + 5] = f8_(f1.y * 16.f);
                    v[half * 8 + 6] = f8_(f1.z * 16.f); v[half * 8 + 7] = f8_(f1.w * 16.f);
                } else {
                    #pragma unroll
                    for (int e = 0; e < 8; ++e) {
                        const int k = kb + e;
                        v[half * 8 + e] = (k < XD) ? f8_(xg[(size_t)row * XD + k] * 16.f) : (unsigned char)0;
                    }
                }
            }
            *reinterpret_cast<uchar16*>(&xsf8[c * 16]) = v;
        }
    }
    // zero ALL of fbL: sizeof(fbL)=2048B = 128 uint4
    if (tid < 128) reinterpret_cast<uint4*>(fbL)[tid] = (uint4){0u, 0u, 0u, 0u};
    __syncthreads();

    layerRf<0, 832, 3>(tid, xsf8, w1t, eb1, actP, nullptr, nullptr, nullptr,
                       1.f / 1024.f, 16.f);
    __syncthreads();
    layerRf<0, 320, 3>(tid, actP, w2t, eb2, actQ, nullptr, nullptr, nullptr,
                       1.f / 1024.f, 16.f);
    __syncthreads();
    layerRf<1, 320, 1>(tid, actQ, w3t, eb3, nullptr, c3L, nullptr, nullptr,
                       1.f / 1024.f, 0.f);
    __syncthreads();

    if (tid < 32) {
        float a = 0.f;
        const int rg = tid >> 4, rl = tid & 15;
        #pragma unroll
        for (int j = 0; j < ZD; ++j) {
            float qm = c3L[tid * 24 + j];
            float qh = c3L[tid * 24 + 10 + j];
            float qv = sp_(qh) + 1e-8f;
            float e  = eps[(size_t)(m0 + tid) * ZD + j];
            float zj = qm + sqrtf(qv) * e;
            fbL[fpi_(rg, rl, j)]      = f8_(zj * zj * 4.f);
            fbL[fpi_(rg, rl, 10 + j)] = f8_(zj * 4.f);
            float d = zj - qm;
            a += __logf(6.283185307179586f * qv) + d * d / qv;
        }
        lqzL[tid] = -0.5f * a;
    }
    __syncthreads();

    layerRf<0, 64, 3>(tid, fbL, d1t, db1, actP, nullptr, nullptr, nullptr,
                      1.f / 64.f, 16.f);
    __syncthreads();
    layerRf<0, 320, 3>(tid, actP, d2t, db2, actQ, nullptr, nullptr, nullptr,
                       1.f / 1024.f, 16.f);
    __syncthreads();
    layerRf<2, 320, 7>(tid, actQ, d3t, db3, nullptr, nullptr, redL,
                       xg + (size_t)m0 * XD, 1.f / 1024.f, 0.f);
    __syncthreads();
    layerCf(tid, fbL, G, cbias, redM, redS);
    __syncthreads();

    if (tid < 32) {
        float M = -1e30f, S = 0.f;
        #pragma unroll
        for (int w16 = 0; w16 < 16; ++w16) {
            float m = redM[tid * 16 + w16], s = redS[tid * 16 + w16];
            float M2 = fmaxf(M, m);
            S = S * __expf(M - M2) + s * __expf(m - M2);
            M = M2;
        }
        float lpz = M + __logf(S) - 7.6009024595420824f;  // log(2000)
        float lpx = 0.f;
        #pragma unroll
        for (int w16 = 0; w16 < 16; ++w16) lpx += redL[tid * 16 + w16];
        float kl = lqzL[tid] - lpz;
        float ne = kl - lpx, re = -lpx;
        #pragma unroll
        for (int d = 1; d <= 16; d <<= 1) {
            ne += __shfl_xor(ne, d); kl += __shfl_xor(kl, d); re += __shfl_xor(re, d);
        }
        if (tid == 0) {
            part[blockIdx.x * 3 + 0] = ne;
            part[blockIdx.x * 3 + 1] = kl;
            part[blockIdx.x * 3 + 2] = re;
        }
    }
}

// ---------------------------------------------------------------------------
// prep (weights only now): fp8 fragment-major (scaled); G (x64) + fp32 cbias.
// Chunk=1KB: 16 cols x 64 k; lane 16B: byte e -> k = kc*64+(e>>3)*32+hi*8+(e&7)
// ---------------------------------------------------------------------------
__global__ __launch_bounds__(256)
void prep_k(const float* __restrict__ ew1, const float* __restrict__ ew2,
            const float* __restrict__ ew3, const float* __restrict__ dw1,
            const float* __restrict__ dw2, const float* __restrict__ dw3,
            const float* __restrict__ zpre,
            unsigned char* __restrict__ w1t, unsigned char* __restrict__ w2t,
            unsigned char* __restrict__ w3t, unsigned char* __restrict__ d1t,
            unsigned char* __restrict__ d2t, unsigned char* __restrict__ d3t,
            unsigned char* __restrict__ G, float* __restrict__ cbias)
{
    const int t = blockIdx.x * 256 + threadIdx.x;
    const int y = blockIdx.y;
    const int lane = t & 63, chunk = t >> 6;
    const int cl = lane & 15, hi = lane >> 4;

    auto genw = [&](const float* W, unsigned char* out, int NT, int KS,
                    int K, int N, float s) {
        if (chunk >= NT * KS) return;
        const int kc = chunk % KS, nt = chunk / KS;
        const int n = nt * 16 + cl;
        uchar16 v;
        #pragma unroll
        for (int e = 0; e < 16; ++e) {
            const int k = kc * 64 + (e >> 3) * 32 + hi * 8 + (e & 7);
            v[e] = f8_((n < N && k < K) ? W[(size_t)k * N + n] * s : 0.f);
        }
        *reinterpret_cast<uchar16*>(&out[(size_t)t * 16]) = v;
    };

    if (y == 0) genw(ew1, w1t, 24, 13, XD, HH, 64.f);
    else if (y == 1) genw(ew2, w2t, 24, 5, HH, HH, 64.f);
    else if (y == 2) genw(ew3, w3t, 8, 5, HH, 2 * ZD, 64.f);
    else if (y == 3) {          // d1t: rows k=10..19 hold dw1 (fb layout), x16
        if (chunk >= 24) return;
        const int n = chunk * 16 + cl;
        uchar16 v;
        #pragma unroll
        for (int e = 0; e < 16; ++e) {
            const int k = (e >> 3) * 32 + hi * 8 + (e & 7);
            float vv = (n < HH && k >= 10 && k < 20) ? dw1[(size_t)(k - 10) * HH + n] * 16.f : 0.f;
            v[e] = f8_(vv);
        }
        *reinterpret_cast<uchar16*>(&d1t[(size_t)t * 16]) = v;
    }
    else if (y == 4) genw(dw2, d2t, 24, 5, HH, HH, 64.f);
    else if (y == 5) genw(dw3, d3t, 56, 5, HH, XD, 64.f);
    else {                      // G x64; fp32 cbias
        if (chunk >= 128) return;
        const int n = chunk * 16 + cl;
        uchar16 v;
        #pragma unroll
        for (int e = 0; e < 16; ++e) {
            const int k = (e >> 3) * 32 + hi * 8 + (e & 7);
            float vv = 0.f;
            if (n < KK) {
                if (k < 10) {
                    float h = zpre[(KK + n) * ZD + k];
                    float vr = sp_(h) + 1e-8f;
                    vv = (-0.5f / vr) * 64.f;
                } else if (k < 20) {
                    float m = zpre[n * ZD + (k - 10)];
                    float h = zpre[(KK + n) * ZD + (k - 10)];
                    float vr = sp_(h) + 1e-8f;
                    vv = (m / vr) * 64.f;
                }
            }
            v[e] = f8_(vv);
        }
        *reinterpret_cast<uchar16*>(&G[(size_t)t * 16]) = v;
        if (hi == 0) {
            float cb = -1e30f;
            if (n < KK) {
                float csum = 0.f;
                #pragma unroll
                for (int j = 0; j < ZD; ++j) {
                    float m = zpre[n * ZD + j];
                    float h = zpre[(KK + n) * ZD + j];
                    float vr = sp_(h) + 1e-8f;
                    csum += __logf(6.283185307179586f * vr) + m * m / vr;
                }
                cb = -0.5f * csum;
            }
            cbias[n] = cb;
        }
    }
}

__global__ void fin_k(const float* __restrict__ part, float* __restrict__ out)
{
    int c = threadIdx.x >> 6, l = threadIdx.x & 63;
    if (c < 3) {
        float s = 0.f;
        for (int i = l; i < 256; i += 64) s += part[i * 3 + c];
        #pragma unroll
        for (int d = 1; d < 64; d <<= 1) s += __shfl_xor(s, d);
        if (l == 0) out[c] = s / (float)BB;
    }
}

extern "C" void kernel_launch(void* const* d_in, const int* in_sizes, int n_in,
                              void* d_out, int out_size, void* d_ws, size_t ws_size,
                              hipStream_t stream)
{
    const float* x    = (const float*)d_in[0];
    const float* eps  = (const float*)d_in[1];
    const float* zpre = (const float*)d_in[2];
    const float* ew1  = (const float*)d_in[3];
    const float* eb1  = (const float*)d_in[4];
    const float* ew2  = (const float*)d_in[5];
    const float* eb2  = (const float*)d_in[6];
    const float* ew3  = (const float*)d_in[7];
    const float* eb3  = (const float*)d_in[8];
    const float* dw1  = (const float*)d_in[9];
    const float* db1  = (const float*)d_in[10];
    const float* dw2  = (const float*)d_in[11];
    const float* db2  = (const float*)d_in[12];
    const float* dw3  = (const float*)d_in[13];
    const float* db3  = (const float*)d_in[14];
    float* out = (float*)d_out;

    float* ws    = (float*)d_ws;
    float* part  = ws;                       // 256*3
    float* cbias = part + 768;               // 2048
    unsigned char* ub = (unsigned char*)(cbias + 2048);
    unsigned char* w1t = ub; ub += 24 * 13 * 1024;
    unsigned char* w2t = ub; ub += 24 * 5 * 1024;
    unsigned char* w3t = ub; ub += 8 * 5 * 1024;
    unsigned char* d1t = ub; ub += 24 * 1 * 1024;
    unsigned char* d2t = ub; ub += 24 * 5 * 1024;
    unsigned char* d3t = ub; ub += 56 * 5 * 1024;
    unsigned char* G   = ub; ub += 128 * 1 * 1024;

    dim3 blk(256);
    prep_k<<<dim3(78, 7), blk, 0, stream>>>(ew1, ew2, ew3, dw1, dw2, dw3, zpre,
                                            w1t, w2t, w3t, d1t, d2t, d3t, G, cbias);
    fused_k<<<256, 1024, 0, stream>>>(x, w1t, eb1, w2t, eb2, w3t, eb3,
                                      d1t, db1, d2t, db2, d3t, db3, G, cbias, eps, part);
    fin_k<<<1, 256, 0, stream>>>(part, out);
}